// Round 4
// baseline (597.526 us; speedup 1.0000x reference)
//
#include <hip/hip_runtime.h>
#include <hip/hip_bf16.h>

// Problem constants
constexpr int Lq = 2048;   // sequence length
constexpr int Dm = 1024;   // model dim
constexpr int Hh = 16;     // heads
constexpr int HD = 64;     // head dim

typedef __bf16 v8bf __attribute__((ext_vector_type(8)));
typedef short  v4s  __attribute__((ext_vector_type(4)));
typedef float  v4f  __attribute__((ext_vector_type(4)));

#define DEV static __device__ __forceinline__

DEV short f2bf(float f) {
  return (short)__builtin_bit_cast(unsigned short, __float2bfloat16(f));
}

DEV v4f MFMA(v8bf a, v8bf b, v4f c) {
  return __builtin_amdgcn_mfma_f32_16x16x32_bf16(a, b, c, 0, 0, 0);
}

// DPP cross-lane (VALU pipe): 16-lane reduce = xor1,xor2,half_mirror,mirror
template<int CTRL>
DEV float dppf(float x) {
  return __builtin_bit_cast(float, __builtin_amdgcn_update_dpp(
      0, __builtin_bit_cast(int, x), CTRL, 0xF, 0xF, true));
}
DEV float rowmax16(float x) {
  x = fmaxf(x, dppf<0xB1>(x));    // quad_perm [1,0,3,2]
  x = fmaxf(x, dppf<0x4E>(x));    // quad_perm [2,3,0,1]
  x = fmaxf(x, dppf<0x141>(x));   // row_half_mirror
  x = fmaxf(x, dppf<0x140>(x));   // row_mirror
  return x;
}
DEV float rowsum16(float x) {
  x += dppf<0xB1>(x);
  x += dppf<0x4E>(x);
  x += dppf<0x141>(x);
  x += dppf<0x140>(x);
  return x;
}

DEV float bperm(int byteaddr, float x) {
  return __builtin_bit_cast(float,
      __builtin_amdgcn_ds_bpermute(byteaddr, __builtin_bit_cast(int, x)));
}

#if __has_builtin(__builtin_amdgcn_exp2f)
DEV float exp2g(float x) { return __builtin_amdgcn_exp2f(x); }
#else
DEV float exp2g(float x) { return exp2f(x); }
#endif

DEV v4s cvt4(float4 v) {
  v4s w; w[0] = f2bf(v.x); w[1] = f2bf(v.y); w[2] = f2bf(v.z); w[3] = f2bf(v.w);
  return w;
}

// ---------------------------------------------------------------------------
// fp32 -> bf16 bulk convert (8 elems/thread)
// ---------------------------------------------------------------------------
__launch_bounds__(256)
__global__ void cvt_bf16(const float* __restrict__ in, short* __restrict__ out,
                         int n8)
{
  int i = blockIdx.x * 256 + threadIdx.x;
  if (i >= n8) return;
  float4 a = *(const float4*)(in + (size_t)i * 8);
  float4 b = *(const float4*)(in + (size_t)i * 8 + 4);
  *(v4s*)(out + (size_t)i * 8)     = cvt4(a);
  *(v4s*)(out + (size_t)i * 8 + 4) = cvt4(b);
}

// ---------------------------------------------------------------------------
// Fused projection GEMM: C[i,o] = sum_k A[i,k]*W[o,k] (+epilogue per z)
// A bf16 (pre-converted), W fp32. 64x64 tile, BK=64, 4 waves.
// z=0: Q -> Qu=y+bq+u, Qv=y+bq+v  (B,H,L,HD)
// z=1: K -> Kb (B,H,L,HD)
// z=2: V -> Vt (B,H,HD,L)  transposed
// z=3: P -> Pb (H,L,HD)    (M=2048: upper half of grid returns)
// ---------------------------------------------------------------------------
__launch_bounds__(256)
__global__ void gemm_qkvp(const short* __restrict__ xb,
                          const short* __restrict__ posb,
                          const float* __restrict__ Wq, const float* __restrict__ Wk,
                          const float* __restrict__ Wv, const float* __restrict__ Wp,
                          const float* __restrict__ bq, const float* __restrict__ bk,
                          const float* __restrict__ bv,
                          const float* __restrict__ pu, const float* __restrict__ pvb,
                          short* __restrict__ Qu, short* __restrict__ Qv,
                          short* __restrict__ Kb, short* __restrict__ Vt,
                          short* __restrict__ Pb)
{
  const int z    = blockIdx.z;
  const int row0 = blockIdx.y * 64;
  const int col0 = blockIdx.x * 64;
  if (z == 3 && row0 >= Lq) return;
  const short* A = (z == 3) ? posb : xb;
  const float* W = (z == 0) ? Wq : (z == 1) ? Wk : (z == 2) ? Wv : Wp;

  __shared__ short As[64][72];   // +8 pad
  __shared__ short Bs[64][72];

  const int tid  = threadIdx.x;
  const int lane = tid & 63;
  const int wave = tid >> 6;
  const int lr   = lane & 15;
  const int lg   = lane >> 4;
  const int wr   = (wave >> 1) * 32;
  const int wc   = (wave & 1) * 32;
  const int srow = tid >> 2;
  const int scol = (tid & 3) * 16;

  v4f acc[2][2] = {};

  for (int k0 = 0; k0 < Dm; k0 += 64) {
    __syncthreads();
    *(v8bf*)(&As[srow][scol]) =
        *(const v8bf*)(A + (size_t)(row0 + srow) * Dm + k0 + scol);
    *(v8bf*)(&As[srow][scol + 8]) =
        *(const v8bf*)(A + (size_t)(row0 + srow) * Dm + k0 + scol + 8);
    #pragma unroll
    for (int i = 0; i < 4; ++i) {
      float4 v = *(const float4*)(W + (size_t)(col0 + srow) * Dm + k0 + scol + i * 4);
      *(v4s*)(&Bs[srow][scol + i * 4]) = cvt4(v);
    }
    __syncthreads();

    #pragma unroll
    for (int kk = 0; kk < 2; ++kk) {
      v8bf af[2], bfr[2];
      #pragma unroll
      for (int sm = 0; sm < 2; ++sm)
        af[sm] = *(const v8bf*)(&As[wr + sm * 16 + lr][kk * 32 + lg * 8]);
      #pragma unroll
      for (int sn = 0; sn < 2; ++sn)
        bfr[sn] = *(const v8bf*)(&Bs[wc + sn * 16 + lr][kk * 32 + lg * 8]);
      #pragma unroll
      for (int sm = 0; sm < 2; ++sm)
        #pragma unroll
        for (int sn = 0; sn < 2; ++sn)
          acc[sm][sn] = MFMA(af[sm], bfr[sn], acc[sm][sn]);
    }
  }

  // ---- epilogue (C frag: col = lane&15, row = (lane>>4)*4 + r) ----
  #pragma unroll
  for (int sm = 0; sm < 2; ++sm) {
    #pragma unroll
    for (int sn = 0; sn < 2; ++sn) {
      #pragma unroll
      for (int r = 0; r < 4; ++r) {
        int i = row0 + wr + sm * 16 + lg * 4 + r;
        int o = col0 + wc + sn * 16 + lr;
        float val = acc[sm][sn][r];
        int b = i >> 11, l = i & 2047;
        int hh = o >> 6, hd = o & 63;
        if (z == 0) {
          val += bq[o];
          size_t idx = (((size_t)(b * Hh + hh)) * Lq + l) * HD + hd;
          Qu[idx] = f2bf(val + pu[o]);
          Qv[idx] = f2bf(val + pvb[o]);
        } else if (z == 1) {
          val += bk[o];
          size_t idx = (((size_t)(b * Hh + hh)) * Lq + l) * HD + hd;
          Kb[idx] = f2bf(val);
        } else if (z == 2) {
          val += bv[o];
          size_t idx = (((size_t)(b * Hh + hh)) * HD + hd) * Lq + l;
          Vt[idx] = f2bf(val);
        } else {
          size_t idx = ((size_t)hh * Lq + i) * HD + hd;
          Pb[idx] = f2bf(val);
        }
      }
    }
  }
}

// ---------------------------------------------------------------------------
// Output GEMM: out = AO @ Wo^T + bo (AO bf16, Wo fp32, out fp32)
// ---------------------------------------------------------------------------
__launch_bounds__(256)
__global__ void gemm_out(const short* __restrict__ A,
                         const float* __restrict__ W,
                         const float* __restrict__ bias,
                         float* __restrict__ out)
{
  __shared__ short As[64][72];
  __shared__ short Bs[64][72];

  const int tid  = threadIdx.x;
  const int lane = tid & 63;
  const int wave = tid >> 6;
  const int lr   = lane & 15;
  const int lg   = lane >> 4;
  const int row0 = blockIdx.y * 64;
  const int col0 = blockIdx.x * 64;
  const int wr   = (wave >> 1) * 32;
  const int wc   = (wave & 1) * 32;
  const int srow = tid >> 2;
  const int scol = (tid & 3) * 16;

  v4f acc[2][2] = {};

  for (int k0 = 0; k0 < Dm; k0 += 64) {
    __syncthreads();
    *(v8bf*)(&As[srow][scol]) =
        *(const v8bf*)(A + (size_t)(row0 + srow) * Dm + k0 + scol);
    *(v8bf*)(&As[srow][scol + 8]) =
        *(const v8bf*)(A + (size_t)(row0 + srow) * Dm + k0 + scol + 8);
    #pragma unroll
    for (int i = 0; i < 4; ++i) {
      float4 v = *(const float4*)(W + (size_t)(col0 + srow) * Dm + k0 + scol + i * 4);
      *(v4s*)(&Bs[srow][scol + i * 4]) = cvt4(v);
    }
    __syncthreads();

    #pragma unroll
    for (int kk = 0; kk < 2; ++kk) {
      v8bf af[2], bfr[2];
      #pragma unroll
      for (int sm = 0; sm < 2; ++sm)
        af[sm] = *(const v8bf*)(&As[wr + sm * 16 + lr][kk * 32 + lg * 8]);
      #pragma unroll
      for (int sn = 0; sn < 2; ++sn)
        bfr[sn] = *(const v8bf*)(&Bs[wc + sn * 16 + lr][kk * 32 + lg * 8]);
      #pragma unroll
      for (int sm = 0; sm < 2; ++sm)
        #pragma unroll
        for (int sn = 0; sn < 2; ++sn)
          acc[sm][sn] = MFMA(af[sm], bfr[sn], acc[sm][sn]);
    }
  }

  #pragma unroll
  for (int sm = 0; sm < 2; ++sm)
    #pragma unroll
    for (int sn = 0; sn < 2; ++sn)
      #pragma unroll
      for (int r = 0; r < 4; ++r) {
        int i = row0 + wr + sm * 16 + lg * 4 + r;
        int o = col0 + wc + sn * 16 + lr;
        out[(size_t)i * Dm + o] = acc[sm][sn][r] + bias[o];
      }
}

// ---------------------------------------------------------------------------
// Barrier-free fused rel-pos flash attention.
// grid (L/64, B*H), block 256 = 4 INDEPENDENT waves (16 q-rows each).
// K/V/P MFMA fragments are read directly from global (L1/L2-resident:
// 256KB per (b,h)); no LDS staging, no __syncthreads. Ps is per-wave-private.
// rel_shift closed form:
//   k <= q   : bd[q,   L-1-q+k]
//   k == q+1 : 0
//   k >  q+1 : bd[q+1, k-q-2]     (row-wrap artifact of the reshape trick)
// Band tiles streamed 2-live; gather = 2 bpermute + cndmask (addr hoisted).
// Softmax: DPP reduces, exp2 domain, exact defer-max (skip identity rescale).
// ---------------------------------------------------------------------------
__launch_bounds__(256)
__global__ void attn_kernel(const short* __restrict__ Qu,
                            const short* __restrict__ Qv,
                            const short* __restrict__ Kb,
                            const short* __restrict__ Vt,
                            const short* __restrict__ Pb,
                            short* __restrict__ AO)
{
  __shared__ short Ps[4][16][72];   // per-wave softmax probs (bf16)

  const int tid  = threadIdx.x;
  const int lane = tid & 63;
  const int wave = tid >> 6;
  const int lr   = lane & 15;
  const int lg   = lane >> 4;
  const int bh   = blockIdx.y;          // b*H + h
  const int h    = bh & (Hh - 1);
  const int q0   = blockIdx.x * 64 + wave * 16;

  const short* Qu_bh = Qu + (size_t)bh * Lq * HD;
  const short* Qv_bh = Qv + (size_t)bh * Lq * HD;
  // per-lane fragment bases
  const short* Kl = Kb + (size_t)bh * Lq * HD + lr * HD + lg * 8;  // + k*HD (+32)
  const short* Vl = Vt + (size_t)bh * HD * Lq + lr * Lq + lg * 8;  // + n*16*Lq + k
  const short* Pl = Pb + (size_t)h * Lq * HD + lg * 8;             // + j*HD (+32)

  // hoisted gather constants: c = lr - dq + 15 in [0,30]
  int  addr4[4];
  bool hi4[4];
  #pragma unroll
  for (int r = 0; r < 4; ++r) {
    int c = lr - (lg * 4 + r) + 15;
    hi4[r]   = (c >= 16);
    addr4[r] = (((lane & 48) | (c & 15)) << 2);
  }

  // Q fragments (A operand): lane holds row (q0+lr), d = kk*32 + lg*8 + e
  v8bf qu[2], qv1[2], qv2[2];
  {
    int q  = q0 + lr;
    int q2 = (q + 1 < Lq) ? q + 1 : Lq - 1;   // clamped row never selected
    #pragma unroll
    for (int kk = 0; kk < 2; ++kk) {
      qu[kk]  = *(const v8bf*)(Qu_bh + (size_t)q  * HD + kk * 32 + lg * 8);
      qv1[kk] = *(const v8bf*)(Qv_bh + (size_t)q  * HD + kk * 32 + lg * 8);
      qv2[kk] = *(const v8bf*)(Qv_bh + (size_t)q2 * HD + kk * 32 + lg * 8);
    }
  }

  float m_r[4], l_r[4];
  v4f o_acc[4];
  #pragma unroll
  for (int r = 0; r < 4; ++r) { m_r[r] = -1e30f; l_r[r] = 0.f; }
  #pragma unroll
  for (int n = 0; n < 4; ++n) o_acc[n] = v4f{0.f, 0.f, 0.f, 0.f};

  const float sc = 0.125f * 1.44269504088896f;   // hd^-0.5 * log2(e)

  for (int k0 = 0; k0 < Lq; k0 += 64) {
    // ---- ac = Qu @ K^T (16x64), K frags direct from global ----
    v4f s[4];
    #pragma unroll
    for (int kt = 0; kt < 4; ++kt) {
      v8bf kb0 = *(const v8bf*)(Kl + (size_t)(k0 + kt * 16) * HD);
      v8bf kb1 = *(const v8bf*)(Kl + (size_t)(k0 + kt * 16) * HD + 32);
      v4f a = MFMA(qu[0], kb0, v4f{0.f, 0.f, 0.f, 0.f});
      s[kt] = MFMA(qu[1], kb1, a);
    }

    // ---- banded bd, streamed 2-live band tiles ----
    const int thr = q0 - k0 + 15;          // select T1 iff cc <= thr
    const int jb1 = 2032 + k0 - q0;        // (Lq-1) - q0 + k0 - 15
    const int jb2 = k0 - q0 - 17;

    auto band = [&](int n) -> v4f {
      v4f a1 = {0.f, 0.f, 0.f, 0.f}, a2 = {0.f, 0.f, 0.f, 0.f};
      if (n * 16 <= thr) {                 // T1 sub-tile live
        int j = jb1 + n * 16 + lr;
        j = j < 0 ? 0 : (j > Lq - 1 ? Lq - 1 : j);
        const short* p = Pl + (size_t)j * HD;
        a1 = MFMA(qv1[0], *(const v8bf*)p, a1);
        a1 = MFMA(qv1[1], *(const v8bf*)(p + 32), a1);
      }
      if (n * 16 + 15 >= thr + 2) {        // T2 sub-tile live
        int j = jb2 + n * 16 + lr;
        j = j < 0 ? 0 : (j > Lq - 1 ? Lq - 1 : j);
        const short* p = Pl + (size_t)j * HD;
        a2 = MFMA(qv2[0], *(const v8bf*)p, a2);
        a2 = MFMA(qv2[1], *(const v8bf*)(p + 32), a2);
      }
      int cc = n * 16 + lr;
      v4f t;
      #pragma unroll
      for (int r = 0; r < 4; ++r)
        t[r] = (cc <= thr) ? a1[r] : ((cc == thr + 1) ? 0.f : a2[r]);
      return t;
    };

    v4f tp = band(0);
    #pragma unroll
    for (int kt = 0; kt < 4; ++kt) {
      v4f tc = band(kt + 1);
      #pragma unroll
      for (int r = 0; r < 4; ++r) {
        float va = bperm(addr4[r], tp[r]);
        float vb = bperm(addr4[r], tc[r]);
        s[kt][r] = (s[kt][r] + (hi4[r] ? vb : va)) * sc;
      }
      tp = tc;
    }

    // ---- V fragment prefetch (hides L2 latency under softmax) ----
    v8bf vf[2][4];
    #pragma unroll
    for (int kk = 0; kk < 2; ++kk)
      #pragma unroll
      for (int n = 0; n < 4; ++n)
        vf[kk][n] = *(const v8bf*)(Vl + (size_t)n * 16 * Lq + k0 + kk * 32);

    // ---- online softmax (exp2 domain, DPP reduces, exact defer-max) ----
    float rmax[4];
    float need = -1e30f;
    #pragma unroll
    for (int r = 0; r < 4; ++r) {
      float m0 = fmaxf(fmaxf(s[0][r], s[1][r]), fmaxf(s[2][r], s[3][r]));
      rmax[r] = rowmax16(m0);
      need = fmaxf(need, rmax[r] - m_r[r]);
    }
    if (!__all(need <= 0.f)) {             // rescale only when max grew
      #pragma unroll
      for (int r = 0; r < 4; ++r) {
        float mnew  = fmaxf(m_r[r], rmax[r]);
        float alpha = exp2g(m_r[r] - mnew);
        m_r[r] = mnew;
        l_r[r] *= alpha;
        #pragma unroll
        for (int n = 0; n < 4; ++n)
          o_acc[n][r] *= alpha;
      }
    }
    #pragma unroll
    for (int r = 0; r < 4; ++r) {
      float rsum = 0.f;
      #pragma unroll
      for (int kt = 0; kt < 4; ++kt) {
        float p = exp2g(s[kt][r] - m_r[r]);
        rsum += p;
        Ps[wave][lg * 4 + r][kt * 16 + lr] = f2bf(p);
      }
      l_r[r] += rowsum16(rsum);
    }
    asm volatile("s_waitcnt lgkmcnt(0)" ::: "memory");
    __builtin_amdgcn_sched_barrier(0);

    // ---- PV: O += P @ V ----
    #pragma unroll
    for (int kk = 0; kk < 2; ++kk) {
      v8bf pa = *(const v8bf*)(&Ps[wave][lr][kk * 32 + lg * 8]);
      #pragma unroll
      for (int n = 0; n < 4; ++n)
        o_acc[n] = MFMA(pa, vf[kk][n], o_acc[n]);
    }
  }

  // ---- normalize + write AO (B, L, H*HD) bf16 ----
  const int b = bh >> 4;
  #pragma unroll
  for (int r = 0; r < 4; ++r) {
    float inv = 1.0f / l_r[r];
    int q = q0 + lg * 4 + r;
    #pragma unroll
    for (int n = 0; n < 4; ++n) {
      int hd = n * 16 + lr;
      AO[((size_t)b * Lq + q) * Dm + h * HD + hd] = f2bf(o_acc[n][r] * inv);
    }
  }
}

// ---------------------------------------------------------------------------
extern "C" void kernel_launch(void* const* d_in, const int* in_sizes, int n_in,
                              void* d_out, int out_size, void* d_ws, size_t ws_size,
                              hipStream_t stream)
{
  (void)in_sizes; (void)n_in; (void)out_size; (void)ws_size;
  const float* x    = (const float*)d_in[0];
  const float* pos  = (const float*)d_in[1];
  const float* Wq   = (const float*)d_in[2];
  const float* bq   = (const float*)d_in[3];
  const float* Wk   = (const float*)d_in[4];
  const float* bk   = (const float*)d_in[5];
  const float* Wv   = (const float*)d_in[6];
  const float* bv   = (const float*)d_in[7];
  const float* Wpos = (const float*)d_in[8];
  const float* pu   = (const float*)d_in[9];
  const float* pvb  = (const float*)d_in[10];
  const float* Wo   = (const float*)d_in[11];
  const float* bo   = (const float*)d_in[12];
  float* out = (float*)d_out;

  // ws layout (shorts): Qu 4M | Qv 4M | Kb 4M | Vt 4M | Pb 2M | AO 4M |
  //                     xb 4M | posb 2M   = 28M shorts = 56 MB
  short* Qu   = (short*)d_ws;
  short* Qv   = Qu   + (size_t)4 * 1024 * 1024;
  short* Kbuf = Qv   + (size_t)4 * 1024 * 1024;
  short* Vt   = Kbuf + (size_t)4 * 1024 * 1024;
  short* Pb   = Vt   + (size_t)4 * 1024 * 1024;
  short* AO   = Pb   + (size_t)2 * 1024 * 1024;
  short* xb   = AO   + (size_t)4 * 1024 * 1024;
  short* posb = xb   + (size_t)4 * 1024 * 1024;

  dim3 blk(256);
  cvt_bf16<<<dim3(2048), blk, 0, stream>>>(x,   xb,   524288);
  cvt_bf16<<<dim3(1024), blk, 0, stream>>>(pos, posb, 262144);
  gemm_qkvp<<<dim3(16, 64, 4), blk, 0, stream>>>(
      xb, posb, Wq, Wk, Wv, Wpos, bq, bk, bv, pu, pvb,
      Qu, Qv, Kbuf, Vt, Pb);
  attn_kernel<<<dim3(Lq / 64, 2 * Hh), blk, 0, stream>>>(Qu, Qv, Kbuf, Vt, Pb, AO);
  gemm_out<<<dim3(16, 64), blk, 0, stream>>>(AO, Wo, bo, out);
}

// Round 5
// 416.649 us; speedup vs baseline: 1.4341x; 1.4341x over previous
//
#include <hip/hip_runtime.h>
#include <hip/hip_bf16.h>

// Problem constants
constexpr int Lq = 2048;   // sequence length
constexpr int Dm = 1024;   // model dim
constexpr int Hh = 16;     // heads
constexpr int HD = 64;     // head dim

typedef __bf16 v8bf __attribute__((ext_vector_type(8)));
typedef short  v4s  __attribute__((ext_vector_type(4)));
typedef float  v4f  __attribute__((ext_vector_type(4)));

#define DEV static __device__ __forceinline__

DEV short f2bf(float f) {
  return (short)__builtin_bit_cast(unsigned short, __float2bfloat16(f));
}

DEV v4f MFMA(v8bf a, v8bf b, v4f c) {
  return __builtin_amdgcn_mfma_f32_16x16x32_bf16(a, b, c, 0, 0, 0);
}

// DPP cross-lane (VALU pipe): 16-lane reduce = xor1,xor2,half_mirror,mirror
template<int CTRL>
DEV float dppf(float x) {
  return __builtin_bit_cast(float, __builtin_amdgcn_update_dpp(
      0, __builtin_bit_cast(int, x), CTRL, 0xF, 0xF, true));
}
DEV float rowmax16(float x) {
  x = fmaxf(x, dppf<0xB1>(x));    // quad_perm [1,0,3,2]
  x = fmaxf(x, dppf<0x4E>(x));    // quad_perm [2,3,0,1]
  x = fmaxf(x, dppf<0x141>(x));   // row_half_mirror
  x = fmaxf(x, dppf<0x140>(x));   // row_mirror
  return x;
}
DEV float rowsum16(float x) {
  x += dppf<0xB1>(x);
  x += dppf<0x4E>(x);
  x += dppf<0x141>(x);
  x += dppf<0x140>(x);
  return x;
}

DEV float bperm(int byteaddr, float x) {
  return __builtin_bit_cast(float,
      __builtin_amdgcn_ds_bpermute(byteaddr, __builtin_bit_cast(int, x)));
}

#if __has_builtin(__builtin_amdgcn_exp2f)
DEV float exp2g(float x) { return __builtin_amdgcn_exp2f(x); }
#else
DEV float exp2g(float x) { return exp2f(x); }
#endif

DEV v4s cvt4(float4 v) {
  v4s w; w[0] = f2bf(v.x); w[1] = f2bf(v.y); w[2] = f2bf(v.z); w[3] = f2bf(v.w);
  return w;
}

// ---------------------------------------------------------------------------
// fp32 -> bf16 bulk convert (8 elems/thread)
// ---------------------------------------------------------------------------
__launch_bounds__(256)
__global__ void cvt_bf16(const float* __restrict__ in, short* __restrict__ out,
                         int n8)
{
  int i = blockIdx.x * 256 + threadIdx.x;
  if (i >= n8) return;
  float4 a = *(const float4*)(in + (size_t)i * 8);
  float4 b = *(const float4*)(in + (size_t)i * 8 + 4);
  *(v4s*)(out + (size_t)i * 8)     = cvt4(a);
  *(v4s*)(out + (size_t)i * 8 + 4) = cvt4(b);
}

// ---------------------------------------------------------------------------
// Fused projection GEMM: C[i,o] = sum_k A[i,k]*W[o,k] (+epilogue per z)
// A bf16 (pre-converted), W fp32. 64x64 tile, BK=64, 4 waves.
// z=0: Q -> Qu=y+bq+u, Qv=y+bq+v  (B,H,L,HD)
// z=1: K -> Kb (B,H,L,HD)
// z=2: V -> Vt (B,H,HD,L)  transposed
// z=3: P -> Pb (H,L,HD)    (M=2048: upper half of grid returns)
// ---------------------------------------------------------------------------
__launch_bounds__(256)
__global__ void gemm_qkvp(const short* __restrict__ xb,
                          const short* __restrict__ posb,
                          const float* __restrict__ Wq, const float* __restrict__ Wk,
                          const float* __restrict__ Wv, const float* __restrict__ Wp,
                          const float* __restrict__ bq, const float* __restrict__ bk,
                          const float* __restrict__ bv,
                          const float* __restrict__ pu, const float* __restrict__ pvb,
                          short* __restrict__ Qu, short* __restrict__ Qv,
                          short* __restrict__ Kb, short* __restrict__ Vt,
                          short* __restrict__ Pb)
{
  const int z    = blockIdx.z;
  const int row0 = blockIdx.y * 64;
  const int col0 = blockIdx.x * 64;
  if (z == 3 && row0 >= Lq) return;
  const short* A = (z == 3) ? posb : xb;
  const float* W = (z == 0) ? Wq : (z == 1) ? Wk : (z == 2) ? Wv : Wp;

  __shared__ short As[64][72];   // +8 pad
  __shared__ short Bs[64][72];

  const int tid  = threadIdx.x;
  const int lane = tid & 63;
  const int wave = tid >> 6;
  const int lr   = lane & 15;
  const int lg   = lane >> 4;
  const int wr   = (wave >> 1) * 32;
  const int wc   = (wave & 1) * 32;
  const int srow = tid >> 2;
  const int scol = (tid & 3) * 16;

  v4f acc[2][2] = {};

  for (int k0 = 0; k0 < Dm; k0 += 64) {
    __syncthreads();
    *(v8bf*)(&As[srow][scol]) =
        *(const v8bf*)(A + (size_t)(row0 + srow) * Dm + k0 + scol);
    *(v8bf*)(&As[srow][scol + 8]) =
        *(const v8bf*)(A + (size_t)(row0 + srow) * Dm + k0 + scol + 8);
    #pragma unroll
    for (int i = 0; i < 4; ++i) {
      float4 v = *(const float4*)(W + (size_t)(col0 + srow) * Dm + k0 + scol + i * 4);
      *(v4s*)(&Bs[srow][scol + i * 4]) = cvt4(v);
    }
    __syncthreads();

    #pragma unroll
    for (int kk = 0; kk < 2; ++kk) {
      v8bf af[2], bfr[2];
      #pragma unroll
      for (int sm = 0; sm < 2; ++sm)
        af[sm] = *(const v8bf*)(&As[wr + sm * 16 + lr][kk * 32 + lg * 8]);
      #pragma unroll
      for (int sn = 0; sn < 2; ++sn)
        bfr[sn] = *(const v8bf*)(&Bs[wc + sn * 16 + lr][kk * 32 + lg * 8]);
      #pragma unroll
      for (int sm = 0; sm < 2; ++sm)
        #pragma unroll
        for (int sn = 0; sn < 2; ++sn)
          acc[sm][sn] = MFMA(af[sm], bfr[sn], acc[sm][sn]);
    }
  }

  // ---- epilogue (C frag: col = lane&15, row = (lane>>4)*4 + r) ----
  #pragma unroll
  for (int sm = 0; sm < 2; ++sm) {
    #pragma unroll
    for (int sn = 0; sn < 2; ++sn) {
      #pragma unroll
      for (int r = 0; r < 4; ++r) {
        int i = row0 + wr + sm * 16 + lg * 4 + r;
        int o = col0 + wc + sn * 16 + lr;
        float val = acc[sm][sn][r];
        int b = i >> 11, l = i & 2047;
        int hh = o >> 6, hd = o & 63;
        if (z == 0) {
          val += bq[o];
          size_t idx = (((size_t)(b * Hh + hh)) * Lq + l) * HD + hd;
          Qu[idx] = f2bf(val + pu[o]);
          Qv[idx] = f2bf(val + pvb[o]);
        } else if (z == 1) {
          val += bk[o];
          size_t idx = (((size_t)(b * Hh + hh)) * Lq + l) * HD + hd;
          Kb[idx] = f2bf(val);
        } else if (z == 2) {
          val += bv[o];
          size_t idx = (((size_t)(b * Hh + hh)) * HD + hd) * Lq + l;
          Vt[idx] = f2bf(val);
        } else {
          size_t idx = ((size_t)hh * Lq + i) * HD + hd;
          Pb[idx] = f2bf(val);
        }
      }
    }
  }
}

// ---------------------------------------------------------------------------
// Output GEMM: out = AO @ Wo^T + bo (AO bf16, Wo fp32, out fp32)
// ---------------------------------------------------------------------------
__launch_bounds__(256)
__global__ void gemm_out(const short* __restrict__ A,
                         const float* __restrict__ W,
                         const float* __restrict__ bias,
                         float* __restrict__ out)
{
  __shared__ short As[64][72];
  __shared__ short Bs[64][72];

  const int tid  = threadIdx.x;
  const int lane = tid & 63;
  const int wave = tid >> 6;
  const int lr   = lane & 15;
  const int lg   = lane >> 4;
  const int row0 = blockIdx.y * 64;
  const int col0 = blockIdx.x * 64;
  const int wr   = (wave >> 1) * 32;
  const int wc   = (wave & 1) * 32;
  const int srow = tid >> 2;
  const int scol = (tid & 3) * 16;

  v4f acc[2][2] = {};

  for (int k0 = 0; k0 < Dm; k0 += 64) {
    __syncthreads();
    *(v8bf*)(&As[srow][scol]) =
        *(const v8bf*)(A + (size_t)(row0 + srow) * Dm + k0 + scol);
    *(v8bf*)(&As[srow][scol + 8]) =
        *(const v8bf*)(A + (size_t)(row0 + srow) * Dm + k0 + scol + 8);
    #pragma unroll
    for (int i = 0; i < 4; ++i) {
      float4 v = *(const float4*)(W + (size_t)(col0 + srow) * Dm + k0 + scol + i * 4);
      *(v4s*)(&Bs[srow][scol + i * 4]) = cvt4(v);
    }
    __syncthreads();

    #pragma unroll
    for (int kk = 0; kk < 2; ++kk) {
      v8bf af[2], bfr[2];
      #pragma unroll
      for (int sm = 0; sm < 2; ++sm)
        af[sm] = *(const v8bf*)(&As[wr + sm * 16 + lr][kk * 32 + lg * 8]);
      #pragma unroll
      for (int sn = 0; sn < 2; ++sn)
        bfr[sn] = *(const v8bf*)(&Bs[wc + sn * 16 + lr][kk * 32 + lg * 8]);
      #pragma unroll
      for (int sm = 0; sm < 2; ++sm)
        #pragma unroll
        for (int sn = 0; sn < 2; ++sn)
          acc[sm][sn] = MFMA(af[sm], bfr[sn], acc[sm][sn]);
    }
  }

  #pragma unroll
  for (int sm = 0; sm < 2; ++sm)
    #pragma unroll
    for (int sn = 0; sn < 2; ++sn)
      #pragma unroll
      for (int r = 0; r < 4; ++r) {
        int i = row0 + wr + sm * 16 + lg * 4 + r;
        int o = col0 + wc + sn * 16 + lr;
        out[(size_t)i * Dm + o] = acc[sm][sn][r] + bias[o];
      }
}

// ---------------------------------------------------------------------------
// Fused rel-pos flash attention, v5.
// grid (L/64, B*H), block 256 (4 waves, 16 q-rows each).
// K: LDS-staged 128 rows/iteration (reg-prefetched 1 iter ahead) -> 2
//    barriers per 128 k (half of R3's rate).
// V: direct-global fragments, prefetched into regs before softmax.
// P: direct-global, software-pipelined 2 band-subtiles ahead; first two
//    subtile loads issued before the QK MFMA block.
// rel_shift closed form:
//   k <= q   : bd[q,   L-1-q+k]
//   k == q+1 : 0
//   k >  q+1 : bd[q+1, k-q-2]     (row-wrap artifact of the reshape trick)
// Softmax: DPP reduces, exp2 domain, exact defer-max (skip identity rescale).
// ---------------------------------------------------------------------------
__launch_bounds__(256)
__global__ void attn_kernel(const short* __restrict__ Qu,
                            const short* __restrict__ Qv,
                            const short* __restrict__ Kb,
                            const short* __restrict__ Vt,
                            const short* __restrict__ Pb,
                            short* __restrict__ AO)
{
  __shared__ short Ks[128][72];     // K tile: rows=k (128), cols=hd (+8 pad)
  __shared__ short Ps[4][16][72];   // per-wave softmax probs (bf16)

  const int tid  = threadIdx.x;
  const int lane = tid & 63;
  const int wave = tid >> 6;
  const int lr   = lane & 15;
  const int lg   = lane >> 4;
  const int bh   = blockIdx.y;          // b*H + h
  const int h    = bh & (Hh - 1);
  const int q0   = blockIdx.x * 64 + wave * 16;

  const short* Qu_bh = Qu + (size_t)bh * Lq * HD;
  const short* Qv_bh = Qv + (size_t)bh * Lq * HD;
  const short* Kb_bh = Kb + (size_t)bh * Lq * HD;
  const short* Vl    = Vt + (size_t)bh * HD * Lq + lr * Lq + lg * 8;
  const short* Pl    = Pb + (size_t)h * Lq * HD + lg * 8;

  // hoisted gather constants: c = lr - dq + 15 in [0,30]
  int  addr4[4];
  bool hi4[4];
  #pragma unroll
  for (int r = 0; r < 4; ++r) {
    int c = lr - (lg * 4 + r) + 15;
    hi4[r]   = (c >= 16);
    addr4[r] = (((lane & 48) | (c & 15)) << 2);
  }

  // Q fragments (A operand): lane holds row (q0+lr), d = kk*32 + lg*8 + e
  v8bf qu[2], qv1[2], qv2[2];
  {
    int q  = q0 + lr;
    int q2 = (q + 1 < Lq) ? q + 1 : Lq - 1;   // clamped row never selected
    #pragma unroll
    for (int kk = 0; kk < 2; ++kk) {
      qu[kk]  = *(const v8bf*)(Qu_bh + (size_t)q  * HD + kk * 32 + lg * 8);
      qv1[kk] = *(const v8bf*)(Qv_bh + (size_t)q  * HD + kk * 32 + lg * 8);
      qv2[kk] = *(const v8bf*)(Qv_bh + (size_t)q2 * HD + kk * 32 + lg * 8);
    }
  }

  // K staging map: thread -> row tid>>1, 64B at col (tid&1)*32 shorts
  const int srow  = tid >> 1;
  const int scolb = (tid & 1) * 32;
  v8bf kpre[4];
  #pragma unroll
  for (int i = 0; i < 4; ++i)
    kpre[i] = *(const v8bf*)(Kb_bh + (size_t)srow * HD + scolb + i * 8);

  float m_r[4], l_r[4];
  v4f o_acc[4];
  #pragma unroll
  for (int r = 0; r < 4; ++r) { m_r[r] = -1e30f; l_r[r] = 0.f; }
  #pragma unroll
  for (int n = 0; n < 4; ++n) o_acc[n] = v4f{0.f, 0.f, 0.f, 0.f};

  const float sc = 0.125f * 1.44269504088896f;   // hd^-0.5 * log2(e)

  for (int kb = 0; kb < Lq; kb += 128) {
    __syncthreads();                       // prev tile's reads done
    #pragma unroll
    for (int i = 0; i < 4; ++i)
      *(v8bf*)(&Ks[srow][scolb + i * 8]) = kpre[i];
    __syncthreads();                       // tile visible
    if (kb + 128 < Lq) {                   // prefetch next K tile
      #pragma unroll
      for (int i = 0; i < 4; ++i)
        kpre[i] = *(const v8bf*)(Kb_bh + (size_t)(kb + 128 + srow) * HD + scolb + i * 8);
    }

    #pragma unroll
    for (int h2 = 0; h2 < 2; ++h2) {
      const int k0  = kb + h2 * 64;
      const int thr = q0 - k0 + 15;        // select T1 iff cc <= thr
      const int jb1 = 2032 + k0 - q0;      // (Lq-1) - q0 + k0 - 15
      const int jb2 = k0 - q0 - 17;

      // band P regs, 2-slot pipeline (slots resolve to regs after inlining)
      v8bf p1[2][2], p2[2][2];
      auto loadB = [&](int n, int slot) {
        if (n * 16 <= thr) {
          int j = jb1 + n * 16 + lr;
          j = j < 0 ? 0 : (j > Lq - 1 ? Lq - 1 : j);
          const short* p = Pl + (size_t)j * HD;
          p1[slot][0] = *(const v8bf*)p;
          p1[slot][1] = *(const v8bf*)(p + 32);
        }
        if (n * 16 + 15 >= thr + 2) {
          int j = jb2 + n * 16 + lr;
          j = j < 0 ? 0 : (j > Lq - 1 ? Lq - 1 : j);
          const short* p = Pl + (size_t)j * HD;
          p2[slot][0] = *(const v8bf*)p;
          p2[slot][1] = *(const v8bf*)(p + 32);
        }
      };
      auto mergeB = [&](int n, int slot) -> v4f {
        v4f a1 = {0.f, 0.f, 0.f, 0.f}, a2 = {0.f, 0.f, 0.f, 0.f};
        if (n * 16 <= thr) {
          a1 = MFMA(qv1[0], p1[slot][0], a1);
          a1 = MFMA(qv1[1], p1[slot][1], a1);
        }
        if (n * 16 + 15 >= thr + 2) {
          a2 = MFMA(qv2[0], p2[slot][0], a2);
          a2 = MFMA(qv2[1], p2[slot][1], a2);
        }
        int cc = n * 16 + lr;
        v4f t;
        #pragma unroll
        for (int r = 0; r < 4; ++r)
          t[r] = (cc <= thr) ? a1[r] : ((cc == thr + 1) ? 0.f : a2[r]);
        return t;
      };

      loadB(0, 0);                         // overlap with QK below
      loadB(1, 1);

      // ---- ac = Qu @ K^T (16x64) from LDS ----
      v4f s[4];
      #pragma unroll
      for (int kt = 0; kt < 4; ++kt) {
        v8bf kf0 = *(const v8bf*)(&Ks[h2 * 64 + kt * 16 + lr][lg * 8]);
        v8bf kf1 = *(const v8bf*)(&Ks[h2 * 64 + kt * 16 + lr][32 + lg * 8]);
        s[kt] = MFMA(qu[1], kf1, MFMA(qu[0], kf0, v4f{0.f, 0.f, 0.f, 0.f}));
      }

      auto gather = [&](int kt, const v4f& tp, const v4f& tc) {
        #pragma unroll
        for (int r = 0; r < 4; ++r) {
          float va = bperm(addr4[r], tp[r]);
          float vb = bperm(addr4[r], tc[r]);
          s[kt][r] = (s[kt][r] + (hi4[r] ? vb : va)) * sc;
        }
      };

      v4f t0 = mergeB(0, 0);
      loadB(2, 0);
      v4f t1 = mergeB(1, 1);
      gather(0, t0, t1);
      loadB(3, 1);
      v4f t2 = mergeB(2, 0);
      gather(1, t1, t2);
      loadB(4, 0);
      v4f t3 = mergeB(3, 1);
      gather(2, t2, t3);
      v4f t4 = mergeB(4, 0);
      gather(3, t3, t4);

      // ---- V fragment prefetch (lands during softmax) ----
      v8bf vf[2][4];
      #pragma unroll
      for (int kk = 0; kk < 2; ++kk)
        #pragma unroll
        for (int n = 0; n < 4; ++n)
          vf[kk][n] = *(const v8bf*)(Vl + (size_t)n * 16 * Lq + k0 + kk * 32);

      // ---- online softmax (exp2 domain, DPP reduces, exact defer-max) ----
      float rmax[4];
      float need = -1e30f;
      #pragma unroll
      for (int r = 0; r < 4; ++r) {
        float m0 = fmaxf(fmaxf(s[0][r], s[1][r]), fmaxf(s[2][r], s[3][r]));
        rmax[r] = rowmax16(m0);
        need = fmaxf(need, rmax[r] - m_r[r]);
      }
      if (!__all(need <= 0.f)) {           // rescale only when a max grew
        #pragma unroll
        for (int r = 0; r < 4; ++r) {
          float mnew  = fmaxf(m_r[r], rmax[r]);
          float alpha = exp2g(m_r[r] - mnew);
          m_r[r] = mnew;
          l_r[r] *= alpha;
          #pragma unroll
          for (int n = 0; n < 4; ++n)
            o_acc[n][r] *= alpha;
        }
      }
      #pragma unroll
      for (int r = 0; r < 4; ++r) {
        float rsum = 0.f;
        #pragma unroll
        for (int kt = 0; kt < 4; ++kt) {
          float p = exp2g(s[kt][r] - m_r[r]);
          rsum += p;
          Ps[wave][lg * 4 + r][kt * 16 + lr] = f2bf(p);
        }
        l_r[r] += rowsum16(rsum);
      }
      asm volatile("s_waitcnt lgkmcnt(0)" ::: "memory");
      __builtin_amdgcn_sched_barrier(0);

      // ---- PV: O += P @ V ----
      #pragma unroll
      for (int kk = 0; kk < 2; ++kk) {
        v8bf pa = *(const v8bf*)(&Ps[wave][lr][kk * 32 + lg * 8]);
        #pragma unroll
        for (int n = 0; n < 4; ++n)
          o_acc[n] = MFMA(pa, vf[kk][n], o_acc[n]);
      }
    }
  }

  // ---- normalize + write AO (B, L, H*HD) bf16 ----
  const int b = bh >> 4;
  #pragma unroll
  for (int r = 0; r < 4; ++r) {
    float inv = 1.0f / l_r[r];
    int q = q0 + lg * 4 + r;
    #pragma unroll
    for (int n = 0; n < 4; ++n) {
      int hd = n * 16 + lr;
      AO[((size_t)b * Lq + q) * Dm + h * HD + hd] = f2bf(o_acc[n][r] * inv);
    }
  }
}

// ---------------------------------------------------------------------------
extern "C" void kernel_launch(void* const* d_in, const int* in_sizes, int n_in,
                              void* d_out, int out_size, void* d_ws, size_t ws_size,
                              hipStream_t stream)
{
  (void)in_sizes; (void)n_in; (void)out_size; (void)ws_size;
  const float* x    = (const float*)d_in[0];
  const float* pos  = (const float*)d_in[1];
  const float* Wq   = (const float*)d_in[2];
  const float* bq   = (const float*)d_in[3];
  const float* Wk   = (const float*)d_in[4];
  const float* bk   = (const float*)d_in[5];
  const float* Wv   = (const float*)d_in[6];
  const float* bv   = (const float*)d_in[7];
  const float* Wpos = (const float*)d_in[8];
  const float* pu   = (const float*)d_in[9];
  const float* pvb  = (const float*)d_in[10];
  const float* Wo   = (const float*)d_in[11];
  const float* bo   = (const float*)d_in[12];
  float* out = (float*)d_out;

  // ws layout (shorts): Qu 4M | Qv 4M | Kb 4M | Vt 4M | Pb 2M | AO 4M |
  //                     xb 4M | posb 2M   = 28M shorts = 56 MB
  short* Qu   = (short*)d_ws;
  short* Qv   = Qu   + (size_t)4 * 1024 * 1024;
  short* Kbuf = Qv   + (size_t)4 * 1024 * 1024;
  short* Vt   = Kbuf + (size_t)4 * 1024 * 1024;
  short* Pb   = Vt   + (size_t)4 * 1024 * 1024;
  short* AO   = Pb   + (size_t)2 * 1024 * 1024;
  short* xb   = AO   + (size_t)4 * 1024 * 1024;
  short* posb = xb   + (size_t)4 * 1024 * 1024;

  dim3 blk(256);
  cvt_bf16<<<dim3(2048), blk, 0, stream>>>(x,   xb,   524288);
  cvt_bf16<<<dim3(1024), blk, 0, stream>>>(pos, posb, 262144);
  gemm_qkvp<<<dim3(16, 64, 4), blk, 0, stream>>>(
      xb, posb, Wq, Wk, Wv, Wpos, bq, bk, bv, pu, pvb,
      Qu, Qv, Kbuf, Vt, Pb);
  attn_kernel<<<dim3(Lq / 64, 2 * Hh), blk, 0, stream>>>(Qu, Qv, Kbuf, Vt, Pb, AO);
  gemm_out<<<dim3(16, 64), blk, 0, stream>>>(AO, Wo, bo, out);
}

// Round 6
// 348.174 us; speedup vs baseline: 1.7162x; 1.1967x over previous
//
#include <hip/hip_runtime.h>
#include <hip/hip_bf16.h>

// Problem constants
constexpr int Lq = 2048;   // sequence length
constexpr int Dm = 1024;   // model dim
constexpr int Hh = 16;     // heads
constexpr int HD = 64;     // head dim

typedef __bf16 v8bf __attribute__((ext_vector_type(8)));
typedef short  v4s  __attribute__((ext_vector_type(4)));
typedef float  v4f  __attribute__((ext_vector_type(4)));

#define DEV static __device__ __forceinline__

DEV short f2bf(float f) {
  return (short)__builtin_bit_cast(unsigned short, __float2bfloat16(f));
}

DEV v4f MFMA(v8bf a, v8bf b, v4f c) {
  return __builtin_amdgcn_mfma_f32_16x16x32_bf16(a, b, c, 0, 0, 0);
}

// DPP cross-lane (VALU pipe): 16-lane reduce = xor1,xor2,half_mirror,mirror
template<int CTRL>
DEV float dppf(float x) {
  return __builtin_bit_cast(float, __builtin_amdgcn_update_dpp(
      0, __builtin_bit_cast(int, x), CTRL, 0xF, 0xF, true));
}
DEV float rowmax16(float x) {
  x = fmaxf(x, dppf<0xB1>(x));    // quad_perm [1,0,3,2]
  x = fmaxf(x, dppf<0x4E>(x));    // quad_perm [2,3,0,1]
  x = fmaxf(x, dppf<0x141>(x));   // row_half_mirror
  x = fmaxf(x, dppf<0x140>(x));   // row_mirror
  return x;
}

DEV float bperm(int byteaddr, float x) {
  return __builtin_bit_cast(float,
      __builtin_amdgcn_ds_bpermute(byteaddr, __builtin_bit_cast(int, x)));
}

#if __has_builtin(__builtin_amdgcn_exp2f)
DEV float exp2g(float x) { return __builtin_amdgcn_exp2f(x); }
#else
DEV float exp2g(float x) { return exp2f(x); }
#endif

DEV v4s cvt4(float4 v) {
  v4s w; w[0] = f2bf(v.x); w[1] = f2bf(v.y); w[2] = f2bf(v.z); w[3] = f2bf(v.w);
  return w;
}

// ---------------------------------------------------------------------------
// fp32 -> bf16 bulk convert (8 elems/thread)
// ---------------------------------------------------------------------------
__launch_bounds__(256)
__global__ void cvt_bf16(const float* __restrict__ in, short* __restrict__ out,
                         int n8)
{
  int i = blockIdx.x * 256 + threadIdx.x;
  if (i >= n8) return;
  float4 a = *(const float4*)(in + (size_t)i * 8);
  float4 b = *(const float4*)(in + (size_t)i * 8 + 4);
  *(v4s*)(out + (size_t)i * 8)     = cvt4(a);
  *(v4s*)(out + (size_t)i * 8 + 4) = cvt4(b);
}

// ---------------------------------------------------------------------------
// Fused projection GEMM: C[i,o] = sum_k A[i,k]*W[o,k] (+epilogue per z)
// A, W bf16 (pre-converted). 64x64 tile, BK=64, 4 waves, reg-prefetched tiles.
// z=0: Q -> Qu=y+bq+u, Qv=y+bq+v  (B,H,L,HD)
// z=1: K -> Kb (B,H,L,HD)
// z=2: V -> Vt (B,H,HD,L)  transposed
// z=3: P -> Pb (H,L,HD)    (M=2048: upper half of grid returns)
// ---------------------------------------------------------------------------
__launch_bounds__(256)
__global__ void gemm_qkvp(const short* __restrict__ xb,
                          const short* __restrict__ posb,
                          const short* __restrict__ Wqb, const short* __restrict__ Wkb,
                          const short* __restrict__ Wvb, const short* __restrict__ Wpb,
                          const float* __restrict__ bq, const float* __restrict__ bk,
                          const float* __restrict__ bv,
                          const float* __restrict__ pu, const float* __restrict__ pvb,
                          short* __restrict__ Qu, short* __restrict__ Qv,
                          short* __restrict__ Kb, short* __restrict__ Vt,
                          short* __restrict__ Pb)
{
  const int z    = blockIdx.z;
  const int row0 = blockIdx.y * 64;
  const int col0 = blockIdx.x * 64;
  if (z == 3 && row0 >= Lq) return;
  const short* A = (z == 3) ? posb : xb;
  const short* W = (z == 0) ? Wqb : (z == 1) ? Wkb : (z == 2) ? Wvb : Wpb;

  __shared__ short As[64][72];   // +8 pad
  __shared__ short Bs[64][72];

  const int tid  = threadIdx.x;
  const int lane = tid & 63;
  const int wave = tid >> 6;
  const int lr   = lane & 15;
  const int lg   = lane >> 4;
  const int wr   = (wave >> 1) * 32;
  const int wc   = (wave & 1) * 32;
  const int srow = tid >> 2;
  const int scol = (tid & 3) * 16;

  const short* Arow = A + (size_t)(row0 + srow) * Dm + scol;
  const short* Wrow = W + (size_t)(col0 + srow) * Dm + scol;

  v8bf a0 = *(const v8bf*)(Arow);
  v8bf a1 = *(const v8bf*)(Arow + 8);
  v8bf b0 = *(const v8bf*)(Wrow);
  v8bf b1 = *(const v8bf*)(Wrow + 8);

  v4f acc[2][2] = {};

  for (int k0 = 0; k0 < Dm; k0 += 64) {
    __syncthreads();
    *(v8bf*)(&As[srow][scol])     = a0;
    *(v8bf*)(&As[srow][scol + 8]) = a1;
    *(v8bf*)(&Bs[srow][scol])     = b0;
    *(v8bf*)(&Bs[srow][scol + 8]) = b1;
    __syncthreads();
    if (k0 + 64 < Dm) {
      a0 = *(const v8bf*)(Arow + k0 + 64);
      a1 = *(const v8bf*)(Arow + k0 + 72);
      b0 = *(const v8bf*)(Wrow + k0 + 64);
      b1 = *(const v8bf*)(Wrow + k0 + 72);
    }

    #pragma unroll
    for (int kk = 0; kk < 2; ++kk) {
      v8bf af[2], bfr[2];
      #pragma unroll
      for (int sm = 0; sm < 2; ++sm)
        af[sm] = *(const v8bf*)(&As[wr + sm * 16 + lr][kk * 32 + lg * 8]);
      #pragma unroll
      for (int sn = 0; sn < 2; ++sn)
        bfr[sn] = *(const v8bf*)(&Bs[wc + sn * 16 + lr][kk * 32 + lg * 8]);
      #pragma unroll
      for (int sm = 0; sm < 2; ++sm)
        #pragma unroll
        for (int sn = 0; sn < 2; ++sn)
          acc[sm][sn] = MFMA(af[sm], bfr[sn], acc[sm][sn]);
    }
  }

  // ---- epilogue (C frag: col = lane&15, row = (lane>>4)*4 + r) ----
  #pragma unroll
  for (int sm = 0; sm < 2; ++sm) {
    #pragma unroll
    for (int sn = 0; sn < 2; ++sn) {
      #pragma unroll
      for (int r = 0; r < 4; ++r) {
        int i = row0 + wr + sm * 16 + lg * 4 + r;
        int o = col0 + wc + sn * 16 + lr;
        float val = acc[sm][sn][r];
        int b = i >> 11, l = i & 2047;
        int hh = o >> 6, hd = o & 63;
        if (z == 0) {
          val += bq[o];
          size_t idx = (((size_t)(b * Hh + hh)) * Lq + l) * HD + hd;
          Qu[idx] = f2bf(val + pu[o]);
          Qv[idx] = f2bf(val + pvb[o]);
        } else if (z == 1) {
          val += bk[o];
          size_t idx = (((size_t)(b * Hh + hh)) * Lq + l) * HD + hd;
          Kb[idx] = f2bf(val);
        } else if (z == 2) {
          val += bv[o];
          size_t idx = (((size_t)(b * Hh + hh)) * HD + hd) * Lq + l;
          Vt[idx] = f2bf(val);
        } else {
          size_t idx = ((size_t)hh * Lq + i) * HD + hd;
          Pb[idx] = f2bf(val);
        }
      }
    }
  }
}

// ---------------------------------------------------------------------------
// Output GEMM: out = AO @ Wo^T + bo (AO, Wo bf16; out fp32)
// ---------------------------------------------------------------------------
__launch_bounds__(256)
__global__ void gemm_out(const short* __restrict__ A,
                         const short* __restrict__ W,
                         const float* __restrict__ bias,
                         float* __restrict__ out)
{
  __shared__ short As[64][72];
  __shared__ short Bs[64][72];

  const int tid  = threadIdx.x;
  const int lane = tid & 63;
  const int wave = tid >> 6;
  const int lr   = lane & 15;
  const int lg   = lane >> 4;
  const int row0 = blockIdx.y * 64;
  const int col0 = blockIdx.x * 64;
  const int wr   = (wave >> 1) * 32;
  const int wc   = (wave & 1) * 32;
  const int srow = tid >> 2;
  const int scol = (tid & 3) * 16;

  const short* Arow = A + (size_t)(row0 + srow) * Dm + scol;
  const short* Wrow = W + (size_t)(col0 + srow) * Dm + scol;

  v8bf a0 = *(const v8bf*)(Arow);
  v8bf a1 = *(const v8bf*)(Arow + 8);
  v8bf b0 = *(const v8bf*)(Wrow);
  v8bf b1 = *(const v8bf*)(Wrow + 8);

  v4f acc[2][2] = {};

  for (int k0 = 0; k0 < Dm; k0 += 64) {
    __syncthreads();
    *(v8bf*)(&As[srow][scol])     = a0;
    *(v8bf*)(&As[srow][scol + 8]) = a1;
    *(v8bf*)(&Bs[srow][scol])     = b0;
    *(v8bf*)(&Bs[srow][scol + 8]) = b1;
    __syncthreads();
    if (k0 + 64 < Dm) {
      a0 = *(const v8bf*)(Arow + k0 + 64);
      a1 = *(const v8bf*)(Arow + k0 + 72);
      b0 = *(const v8bf*)(Wrow + k0 + 64);
      b1 = *(const v8bf*)(Wrow + k0 + 72);
    }

    #pragma unroll
    for (int kk = 0; kk < 2; ++kk) {
      v8bf af[2], bfr[2];
      #pragma unroll
      for (int sm = 0; sm < 2; ++sm)
        af[sm] = *(const v8bf*)(&As[wr + sm * 16 + lr][kk * 32 + lg * 8]);
      #pragma unroll
      for (int sn = 0; sn < 2; ++sn)
        bfr[sn] = *(const v8bf*)(&Bs[wc + sn * 16 + lr][kk * 32 + lg * 8]);
      #pragma unroll
      for (int sm = 0; sm < 2; ++sm)
        #pragma unroll
        for (int sn = 0; sn < 2; ++sn)
          acc[sm][sn] = MFMA(af[sm], bfr[sn], acc[sm][sn]);
    }
  }

  #pragma unroll
  for (int sm = 0; sm < 2; ++sm)
    #pragma unroll
    for (int sn = 0; sn < 2; ++sn)
      #pragma unroll
      for (int r = 0; r < 4; ++r) {
        int i = row0 + wr + sm * 16 + lg * 4 + r;
        int o = col0 + wc + sn * 16 + lr;
        out[(size_t)i * Dm + o] = acc[sm][sn][r] + bias[o];
      }
}

// ---------------------------------------------------------------------------
// Fused rel-pos flash attention, v6 = R3 structure + proven grafts.
// grid (L/64, B*H), block 256 (4 waves, 16 q-rows each).
// K,V: LDS-staged 64 rows/iter, reg-prefetched one tile ahead (R3).
// P: direct-global, 2-slot software pipeline issued under the QK MFMAs (R5).
// l: accumulated as a 5th PV column via MFMA(pa, ones) -- no rowsum16.
// Softmax: DPP rowmax, exp2 domain, exact defer-max (skip identity rescale).
// rel_shift closed form:
//   k <= q   : bd[q,   L-1-q+k]
//   k == q+1 : 0
//   k >  q+1 : bd[q+1, k-q-2]     (row-wrap artifact of the reshape trick)
// ---------------------------------------------------------------------------
__launch_bounds__(256)
__global__ void attn_kernel(const short* __restrict__ Qu,
                            const short* __restrict__ Qv,
                            const short* __restrict__ Kb,
                            const short* __restrict__ Vt,
                            const short* __restrict__ Pb,
                            short* __restrict__ AO)
{
  __shared__ short Ks[64][72];      // K tile: rows=k, cols=hd (+8 pad)
  __shared__ short Vs[64][72];      // V^T tile: rows=hd, cols=k
  __shared__ short Ps[4][16][72];   // per-wave softmax probs (bf16)

  const int tid  = threadIdx.x;
  const int lane = tid & 63;
  const int wave = tid >> 6;
  const int lr   = lane & 15;
  const int lg   = lane >> 4;
  const int bh   = blockIdx.y;          // b*H + h
  const int h    = bh & (Hh - 1);
  const int q0   = blockIdx.x * 64 + wave * 16;

  const short* Qu_bh = Qu + (size_t)bh * Lq * HD;
  const short* Qv_bh = Qv + (size_t)bh * Lq * HD;
  const short* Kb_bh = Kb + (size_t)bh * Lq * HD;
  const short* Vt_bh = Vt + (size_t)bh * HD * Lq;
  const short* Pl    = Pb + (size_t)h * Lq * HD + lg * 8;

  // hoisted gather constants: c = lr - dq + 15 in [0,30]
  int  addr4[4];
  bool hi4[4];
  #pragma unroll
  for (int r = 0; r < 4; ++r) {
    int c = lr - (lg * 4 + r) + 15;
    hi4[r]   = (c >= 16);
    addr4[r] = (((lane & 48) | (c & 15)) << 2);
  }

  // Q fragments (A operand): lane holds row (q0+lr), d = kk*32 + lg*8 + e
  v8bf qu[2], qv1[2], qv2[2];
  {
    int q  = q0 + lr;
    int q2 = (q + 1 < Lq) ? q + 1 : Lq - 1;   // clamped row never selected
    #pragma unroll
    for (int kk = 0; kk < 2; ++kk) {
      qu[kk]  = *(const v8bf*)(Qu_bh + (size_t)q  * HD + kk * 32 + lg * 8);
      qv1[kk] = *(const v8bf*)(Qv_bh + (size_t)q  * HD + kk * 32 + lg * 8);
      qv2[kk] = *(const v8bf*)(Qv_bh + (size_t)q2 * HD + kk * 32 + lg * 8);
    }
  }

  // K/V staging: thread -> row tid>>2, 16 cols at (tid&3)*16 (2 v8bf each)
  const int srow = tid >> 2;
  const int scol = (tid & 3) * 16;
  v8bf kpre0 = *(const v8bf*)(Kb_bh + (size_t)srow * HD + scol);
  v8bf kpre1 = *(const v8bf*)(Kb_bh + (size_t)srow * HD + scol + 8);
  v8bf vpre0 = *(const v8bf*)(Vt_bh + (size_t)srow * Lq + scol);
  v8bf vpre1 = *(const v8bf*)(Vt_bh + (size_t)srow * Lq + scol + 8);

  float m_r[4];
  v4f o_acc[5];                     // [0..3]=O columns, [4]=l (P @ ones)
  #pragma unroll
  for (int r = 0; r < 4; ++r) m_r[r] = -1e30f;
  #pragma unroll
  for (int n = 0; n < 5; ++n) o_acc[n] = v4f{0.f, 0.f, 0.f, 0.f};

  v8bf ones;
  #pragma unroll
  for (int e = 0; e < 8; ++e) ones[e] = (__bf16)1.0f;

  const float sc = 0.125f * 1.44269504088896f;   // hd^-0.5 * log2(e)

  for (int k0 = 0; k0 < Lq; k0 += 64) {
    __syncthreads();                       // prev tile's reads done
    *(v8bf*)(&Ks[srow][scol])     = kpre0;
    *(v8bf*)(&Ks[srow][scol + 8]) = kpre1;
    *(v8bf*)(&Vs[srow][scol])     = vpre0;
    *(v8bf*)(&Vs[srow][scol + 8]) = vpre1;
    __syncthreads();                       // tile visible
    if (k0 + 64 < Lq) {                    // prefetch next K/V tile
      kpre0 = *(const v8bf*)(Kb_bh + (size_t)(k0 + 64 + srow) * HD + scol);
      kpre1 = *(const v8bf*)(Kb_bh + (size_t)(k0 + 64 + srow) * HD + scol + 8);
      vpre0 = *(const v8bf*)(Vt_bh + (size_t)srow * Lq + k0 + 64 + scol);
      vpre1 = *(const v8bf*)(Vt_bh + (size_t)srow * Lq + k0 + 64 + scol + 8);
    }

    const int thr = q0 - k0 + 15;          // select T1 iff cc <= thr
    const int jb1 = 2032 + k0 - q0;        // (Lq-1) - q0 + k0 - 15
    const int jb2 = k0 - q0 - 17;

    // band P regs, 2-slot pipeline (static indices -> registers)
    v8bf p1[2][2], p2[2][2];
    auto loadB = [&](int n, int slot) {
      if (n * 16 <= thr) {
        int j = jb1 + n * 16 + lr;
        j = j < 0 ? 0 : (j > Lq - 1 ? Lq - 1 : j);
        const short* p = Pl + (size_t)j * HD;
        p1[slot][0] = *(const v8bf*)p;
        p1[slot][1] = *(const v8bf*)(p + 32);
      }
      if (n * 16 + 15 >= thr + 2) {
        int j = jb2 + n * 16 + lr;
        j = j < 0 ? 0 : (j > Lq - 1 ? Lq - 1 : j);
        const short* p = Pl + (size_t)j * HD;
        p2[slot][0] = *(const v8bf*)p;
        p2[slot][1] = *(const v8bf*)(p + 32);
      }
    };
    auto mergeB = [&](int n, int slot) -> v4f {
      v4f a1 = {0.f, 0.f, 0.f, 0.f}, a2 = {0.f, 0.f, 0.f, 0.f};
      if (n * 16 <= thr) {
        a1 = MFMA(qv1[0], p1[slot][0], a1);
        a1 = MFMA(qv1[1], p1[slot][1], a1);
      }
      if (n * 16 + 15 >= thr + 2) {
        a2 = MFMA(qv2[0], p2[slot][0], a2);
        a2 = MFMA(qv2[1], p2[slot][1], a2);
      }
      int cc = n * 16 + lr;
      v4f t;
      #pragma unroll
      for (int r = 0; r < 4; ++r)
        t[r] = (cc <= thr) ? a1[r] : ((cc == thr + 1) ? 0.f : a2[r]);
      return t;
    };

    loadB(0, 0);                           // issue under QK below
    loadB(1, 1);

    // ---- ac = Qu @ K^T (16x64) from LDS ----
    v4f s[4];
    #pragma unroll
    for (int kt = 0; kt < 4; ++kt) {
      v8bf kf0 = *(const v8bf*)(&Ks[kt * 16 + lr][lg * 8]);
      v8bf kf1 = *(const v8bf*)(&Ks[kt * 16 + lr][32 + lg * 8]);
      s[kt] = MFMA(qu[1], kf1, MFMA(qu[0], kf0, v4f{0.f, 0.f, 0.f, 0.f}));
    }

    auto gather = [&](int kt, const v4f& tp, const v4f& tc) {
      #pragma unroll
      for (int r = 0; r < 4; ++r) {
        float va = bperm(addr4[r], tp[r]);
        float vb = bperm(addr4[r], tc[r]);
        s[kt][r] = (s[kt][r] + (hi4[r] ? vb : va)) * sc;
      }
    };

    v4f t0 = mergeB(0, 0);
    loadB(2, 0);
    v4f t1 = mergeB(1, 1);
    gather(0, t0, t1);
    loadB(3, 1);
    v4f t2 = mergeB(2, 0);
    gather(1, t1, t2);
    loadB(4, 0);
    v4f t3 = mergeB(3, 1);
    gather(2, t2, t3);
    v4f t4 = mergeB(4, 0);
    gather(3, t3, t4);

    // ---- online softmax (exp2 domain, DPP rowmax, exact defer-max) ----
    float rmax[4];
    float need = -1e30f;
    #pragma unroll
    for (int r = 0; r < 4; ++r) {
      float m0 = fmaxf(fmaxf(s[0][r], s[1][r]), fmaxf(s[2][r], s[3][r]));
      rmax[r] = rowmax16(m0);
      need = fmaxf(need, rmax[r] - m_r[r]);
    }
    if (!__all(need <= 0.f)) {             // rescale only when a max grew
      #pragma unroll
      for (int r = 0; r < 4; ++r) {
        float mnew  = fmaxf(m_r[r], rmax[r]);
        float alpha = exp2g(m_r[r] - mnew);
        m_r[r] = mnew;
        #pragma unroll
        for (int n = 0; n < 5; ++n)
          o_acc[n][r] *= alpha;
      }
    }
    #pragma unroll
    for (int r = 0; r < 4; ++r) {
      #pragma unroll
      for (int kt = 0; kt < 4; ++kt) {
        float p = exp2g(s[kt][r] - m_r[r]);
        Ps[wave][lg * 4 + r][kt * 16 + lr] = f2bf(p);
      }
    }
    asm volatile("s_waitcnt lgkmcnt(0)" ::: "memory");
    __builtin_amdgcn_sched_barrier(0);

    // ---- PV: O += P @ V, l += P @ 1 ----
    #pragma unroll
    for (int kk = 0; kk < 2; ++kk) {
      v8bf pa = *(const v8bf*)(&Ps[wave][lr][kk * 32 + lg * 8]);
      #pragma unroll
      for (int n = 0; n < 4; ++n) {
        v8bf vb = *(const v8bf*)(&Vs[n * 16 + lr][kk * 32 + lg * 8]);
        o_acc[n] = MFMA(pa, vb, o_acc[n]);
      }
      o_acc[4] = MFMA(pa, ones, o_acc[4]);
    }
  }

  // ---- normalize + write AO (B, L, H*HD) bf16 ----
  const int b = bh >> 4;
  #pragma unroll
  for (int r = 0; r < 4; ++r) {
    float inv = 1.0f / o_acc[4][r];
    int q = q0 + lg * 4 + r;
    #pragma unroll
    for (int n = 0; n < 4; ++n) {
      int hd = n * 16 + lr;
      AO[((size_t)b * Lq + q) * Dm + h * HD + hd] = f2bf(o_acc[n][r] * inv);
    }
  }
}

// ---------------------------------------------------------------------------
extern "C" void kernel_launch(void* const* d_in, const int* in_sizes, int n_in,
                              void* d_out, int out_size, void* d_ws, size_t ws_size,
                              hipStream_t stream)
{
  (void)in_sizes; (void)n_in; (void)out_size; (void)ws_size;
  const float* x    = (const float*)d_in[0];
  const float* pos  = (const float*)d_in[1];
  const float* Wq   = (const float*)d_in[2];
  const float* bq   = (const float*)d_in[3];
  const float* Wk   = (const float*)d_in[4];
  const float* bk   = (const float*)d_in[5];
  const float* Wv   = (const float*)d_in[6];
  const float* bv   = (const float*)d_in[7];
  const float* Wpos = (const float*)d_in[8];
  const float* pu   = (const float*)d_in[9];
  const float* pvb  = (const float*)d_in[10];
  const float* Wo   = (const float*)d_in[11];
  const float* bo   = (const float*)d_in[12];
  float* out = (float*)d_out;

  // ws layout (shorts), 56 MB total:
  //   Qu 4M | Qv 4M | Kb 4M | Vt 4M | Pb 2M | AO 4M | xb 4M | posb 2M
  // Aliases (stream-ordered, lifetime-disjoint):
  //   Wqb/Wkb/Wvb/Wpb (1M each) live in AO until attn writes AO;
  //   Wob (1M) lives in xb after gemm_qkvp is done with xb.
  short* Qu   = (short*)d_ws;
  short* Qv   = Qu   + (size_t)4 * 1024 * 1024;
  short* Kbuf = Qv   + (size_t)4 * 1024 * 1024;
  short* Vt   = Kbuf + (size_t)4 * 1024 * 1024;
  short* Pb   = Vt   + (size_t)4 * 1024 * 1024;
  short* AO   = Pb   + (size_t)2 * 1024 * 1024;
  short* xb   = AO   + (size_t)4 * 1024 * 1024;
  short* posb = xb   + (size_t)4 * 1024 * 1024;
  short* Wqb  = AO;
  short* Wkb  = AO + (size_t)1 * 1024 * 1024;
  short* Wvb  = AO + (size_t)2 * 1024 * 1024;
  short* Wpb  = AO + (size_t)3 * 1024 * 1024;
  short* Wob  = xb;

  dim3 blk(256);
  cvt_bf16<<<dim3(2048), blk, 0, stream>>>(x,    xb,   524288);
  cvt_bf16<<<dim3(1024), blk, 0, stream>>>(pos,  posb, 262144);
  cvt_bf16<<<dim3(512),  blk, 0, stream>>>(Wq,   Wqb,  131072);
  cvt_bf16<<<dim3(512),  blk, 0, stream>>>(Wk,   Wkb,  131072);
  cvt_bf16<<<dim3(512),  blk, 0, stream>>>(Wv,   Wvb,  131072);
  cvt_bf16<<<dim3(512),  blk, 0, stream>>>(Wpos, Wpb,  131072);
  gemm_qkvp<<<dim3(16, 64, 4), blk, 0, stream>>>(
      xb, posb, Wqb, Wkb, Wvb, Wpb, bq, bk, bv, pu, pvb,
      Qu, Qv, Kbuf, Vt, Pb);
  cvt_bf16<<<dim3(512),  blk, 0, stream>>>(Wo,   Wob,  131072);
  attn_kernel<<<dim3(Lq / 64, 2 * Hh), blk, 0, stream>>>(Qu, Qv, Kbuf, Vt, Pb, AO);
  gemm_out<<<dim3(16, 64), blk, 0, stream>>>(AO, Wob, bo, out);
}

// Round 7
// 339.893 us; speedup vs baseline: 1.7580x; 1.0244x over previous
//
#include <hip/hip_runtime.h>
#include <hip/hip_bf16.h>

// Problem constants
constexpr int Lq = 2048;   // sequence length
constexpr int Dm = 1024;   // model dim
constexpr int Hh = 16;     // heads
constexpr int HD = 64;     // head dim

typedef __bf16 v8bf __attribute__((ext_vector_type(8)));
typedef short  v4s  __attribute__((ext_vector_type(4)));
typedef float  v4f  __attribute__((ext_vector_type(4)));

#define DEV static __device__ __forceinline__

DEV short f2bf(float f) {
  return (short)__builtin_bit_cast(unsigned short, __float2bfloat16(f));
}

DEV v4f MFMA(v8bf a, v8bf b, v4f c) {
  return __builtin_amdgcn_mfma_f32_16x16x32_bf16(a, b, c, 0, 0, 0);
}

// DPP cross-lane (VALU pipe): 16-lane reduce = xor1,xor2,half_mirror,mirror
template<int CTRL>
DEV float dppf(float x) {
  return __builtin_bit_cast(float, __builtin_amdgcn_update_dpp(
      0, __builtin_bit_cast(int, x), CTRL, 0xF, 0xF, true));
}
DEV float rowmax16(float x) {
  x = fmaxf(x, dppf<0xB1>(x));    // quad_perm [1,0,3,2]
  x = fmaxf(x, dppf<0x4E>(x));    // quad_perm [2,3,0,1]
  x = fmaxf(x, dppf<0x141>(x));   // row_half_mirror
  x = fmaxf(x, dppf<0x140>(x));   // row_mirror
  return x;
}

DEV float bperm(int byteaddr, float x) {
  return __builtin_bit_cast(float,
      __builtin_amdgcn_ds_bpermute(byteaddr, __builtin_bit_cast(int, x)));
}

#if __has_builtin(__builtin_amdgcn_exp2f)
DEV float exp2g(float x) { return __builtin_amdgcn_exp2f(x); }
#else
DEV float exp2g(float x) { return exp2f(x); }
#endif

DEV v4s cvt4(float4 v) {
  v4s w; w[0] = f2bf(v.x); w[1] = f2bf(v.y); w[2] = f2bf(v.z); w[3] = f2bf(v.w);
  return w;
}

// ---------------------------------------------------------------------------
// fp32 -> bf16 bulk convert (8 elems/thread)
// ---------------------------------------------------------------------------
__launch_bounds__(256)
__global__ void cvt_bf16(const float* __restrict__ in, short* __restrict__ out,
                         int n8)
{
  int i = blockIdx.x * 256 + threadIdx.x;
  if (i >= n8) return;
  float4 a = *(const float4*)(in + (size_t)i * 8);
  float4 b = *(const float4*)(in + (size_t)i * 8 + 4);
  *(v4s*)(out + (size_t)i * 8)     = cvt4(a);
  *(v4s*)(out + (size_t)i * 8 + 4) = cvt4(b);
}

// ---------------------------------------------------------------------------
// Fused projection GEMM: C[i,o] = sum_k A[i,k]*W[o,k] (+epilogue per z)
// A, W bf16 (pre-converted). 64x64 tile, BK=64, 4 waves, reg-prefetched tiles.
// z=0: Q -> Qu=y+bq+u, Qv=y+bq+v  (B,H,L,HD)
// z=1: K -> Kb (B,H,L,HD)
// z=2: V -> Vt (B,H,HD,L)  transposed
// z=3: P -> Pb (H,L,HD)    (M=2048: upper half of grid returns)
// ---------------------------------------------------------------------------
__launch_bounds__(256)
__global__ void gemm_qkvp(const short* __restrict__ xb,
                          const short* __restrict__ posb,
                          const short* __restrict__ Wqb, const short* __restrict__ Wkb,
                          const short* __restrict__ Wvb, const short* __restrict__ Wpb,
                          const float* __restrict__ bq, const float* __restrict__ bk,
                          const float* __restrict__ bv,
                          const float* __restrict__ pu, const float* __restrict__ pvb,
                          short* __restrict__ Qu, short* __restrict__ Qv,
                          short* __restrict__ Kb, short* __restrict__ Vt,
                          short* __restrict__ Pb)
{
  const int z    = blockIdx.z;
  const int row0 = blockIdx.y * 64;
  const int col0 = blockIdx.x * 64;
  if (z == 3 && row0 >= Lq) return;
  const short* A = (z == 3) ? posb : xb;
  const short* W = (z == 0) ? Wqb : (z == 1) ? Wkb : (z == 2) ? Wvb : Wpb;

  __shared__ short As[64][72];   // +8 pad
  __shared__ short Bs[64][72];

  const int tid  = threadIdx.x;
  const int lane = tid & 63;
  const int wave = tid >> 6;
  const int lr   = lane & 15;
  const int lg   = lane >> 4;
  const int wr   = (wave >> 1) * 32;
  const int wc   = (wave & 1) * 32;
  const int srow = tid >> 2;
  const int scol = (tid & 3) * 16;

  const short* Arow = A + (size_t)(row0 + srow) * Dm + scol;
  const short* Wrow = W + (size_t)(col0 + srow) * Dm + scol;

  v8bf a0 = *(const v8bf*)(Arow);
  v8bf a1 = *(const v8bf*)(Arow + 8);
  v8bf b0 = *(const v8bf*)(Wrow);
  v8bf b1 = *(const v8bf*)(Wrow + 8);

  v4f acc[2][2] = {};

  for (int k0 = 0; k0 < Dm; k0 += 64) {
    __syncthreads();
    *(v8bf*)(&As[srow][scol])     = a0;
    *(v8bf*)(&As[srow][scol + 8]) = a1;
    *(v8bf*)(&Bs[srow][scol])     = b0;
    *(v8bf*)(&Bs[srow][scol + 8]) = b1;
    __syncthreads();
    if (k0 + 64 < Dm) {
      a0 = *(const v8bf*)(Arow + k0 + 64);
      a1 = *(const v8bf*)(Arow + k0 + 72);
      b0 = *(const v8bf*)(Wrow + k0 + 64);
      b1 = *(const v8bf*)(Wrow + k0 + 72);
    }

    #pragma unroll
    for (int kk = 0; kk < 2; ++kk) {
      v8bf af[2], bfr[2];
      #pragma unroll
      for (int sm = 0; sm < 2; ++sm)
        af[sm] = *(const v8bf*)(&As[wr + sm * 16 + lr][kk * 32 + lg * 8]);
      #pragma unroll
      for (int sn = 0; sn < 2; ++sn)
        bfr[sn] = *(const v8bf*)(&Bs[wc + sn * 16 + lr][kk * 32 + lg * 8]);
      #pragma unroll
      for (int sm = 0; sm < 2; ++sm)
        #pragma unroll
        for (int sn = 0; sn < 2; ++sn)
          acc[sm][sn] = MFMA(af[sm], bfr[sn], acc[sm][sn]);
    }
  }

  // ---- epilogue (C frag: col = lane&15, row = (lane>>4)*4 + r) ----
  #pragma unroll
  for (int sm = 0; sm < 2; ++sm) {
    #pragma unroll
    for (int sn = 0; sn < 2; ++sn) {
      #pragma unroll
      for (int r = 0; r < 4; ++r) {
        int i = row0 + wr + sm * 16 + lg * 4 + r;
        int o = col0 + wc + sn * 16 + lr;
        float val = acc[sm][sn][r];
        int b = i >> 11, l = i & 2047;
        int hh = o >> 6, hd = o & 63;
        if (z == 0) {
          val += bq[o];
          size_t idx = (((size_t)(b * Hh + hh)) * Lq + l) * HD + hd;
          Qu[idx] = f2bf(val + pu[o]);
          Qv[idx] = f2bf(val + pvb[o]);
        } else if (z == 1) {
          val += bk[o];
          size_t idx = (((size_t)(b * Hh + hh)) * Lq + l) * HD + hd;
          Kb[idx] = f2bf(val);
        } else if (z == 2) {
          val += bv[o];
          size_t idx = (((size_t)(b * Hh + hh)) * HD + hd) * Lq + l;
          Vt[idx] = f2bf(val);
        } else {
          size_t idx = ((size_t)hh * Lq + i) * HD + hd;
          Pb[idx] = f2bf(val);
        }
      }
    }
  }
}

// ---------------------------------------------------------------------------
// Output GEMM: out = AO @ Wo^T + bo (AO, Wo bf16; out fp32)
// ---------------------------------------------------------------------------
__launch_bounds__(256)
__global__ void gemm_out(const short* __restrict__ A,
                         const short* __restrict__ W,
                         const float* __restrict__ bias,
                         float* __restrict__ out)
{
  __shared__ short As[64][72];
  __shared__ short Bs[64][72];

  const int tid  = threadIdx.x;
  const int lane = tid & 63;
  const int wave = tid >> 6;
  const int lr   = lane & 15;
  const int lg   = lane >> 4;
  const int row0 = blockIdx.y * 64;
  const int col0 = blockIdx.x * 64;
  const int wr   = (wave >> 1) * 32;
  const int wc   = (wave & 1) * 32;
  const int srow = tid >> 2;
  const int scol = (tid & 3) * 16;

  const short* Arow = A + (size_t)(row0 + srow) * Dm + scol;
  const short* Wrow = W + (size_t)(col0 + srow) * Dm + scol;

  v8bf a0 = *(const v8bf*)(Arow);
  v8bf a1 = *(const v8bf*)(Arow + 8);
  v8bf b0 = *(const v8bf*)(Wrow);
  v8bf b1 = *(const v8bf*)(Wrow + 8);

  v4f acc[2][2] = {};

  for (int k0 = 0; k0 < Dm; k0 += 64) {
    __syncthreads();
    *(v8bf*)(&As[srow][scol])     = a0;
    *(v8bf*)(&As[srow][scol + 8]) = a1;
    *(v8bf*)(&Bs[srow][scol])     = b0;
    *(v8bf*)(&Bs[srow][scol + 8]) = b1;
    __syncthreads();
    if (k0 + 64 < Dm) {
      a0 = *(const v8bf*)(Arow + k0 + 64);
      a1 = *(const v8bf*)(Arow + k0 + 72);
      b0 = *(const v8bf*)(Wrow + k0 + 64);
      b1 = *(const v8bf*)(Wrow + k0 + 72);
    }

    #pragma unroll
    for (int kk = 0; kk < 2; ++kk) {
      v8bf af[2], bfr[2];
      #pragma unroll
      for (int sm = 0; sm < 2; ++sm)
        af[sm] = *(const v8bf*)(&As[wr + sm * 16 + lr][kk * 32 + lg * 8]);
      #pragma unroll
      for (int sn = 0; sn < 2; ++sn)
        bfr[sn] = *(const v8bf*)(&Bs[wc + sn * 16 + lr][kk * 32 + lg * 8]);
      #pragma unroll
      for (int sm = 0; sm < 2; ++sm)
        #pragma unroll
        for (int sn = 0; sn < 2; ++sn)
          acc[sm][sn] = MFMA(af[sm], bfr[sn], acc[sm][sn]);
    }
  }

  #pragma unroll
  for (int sm = 0; sm < 2; ++sm)
    #pragma unroll
    for (int sn = 0; sn < 2; ++sn)
      #pragma unroll
      for (int r = 0; r < 4; ++r) {
        int i = row0 + wr + sm * 16 + lg * 4 + r;
        int o = col0 + wc + sn * 16 + lr;
        out[(size_t)i * Dm + o] = acc[sm][sn][r] + bias[o];
      }
}

// ---------------------------------------------------------------------------
// Fused rel-pos flash attention, v7 = v6 + XCD-aware block swizzle + bperm
// reuse.
// Flat grid of 1024 blocks; swz = (fid&7)*128 + fid>>3 gives each XCD a
// contiguous chunk of 128 blocks = 4 (b,h) pairs -> K/V/P working set
// ~3 MB <= 4 MB per-XCD L2 (was ~20 MB: every P band load missed to L3).
// K,V: LDS-staged 64 rows/iter, reg-prefetched one tile ahead.
// P: direct-global (now L2-hit), 2-slot pipeline issued under the QK MFMAs.
// l: accumulated as a 5th PV column via MFMA(pa, ones).
// Softmax: DPP rowmax, exp2 domain, exact defer-max (skip identity rescale).
// rel_shift closed form:
//   k <= q   : bd[q,   L-1-q+k]
//   k == q+1 : 0
//   k >  q+1 : bd[q+1, k-q-2]     (row-wrap artifact of the reshape trick)
// Gather: g[n] = bperm(t[n]) is shared between kt=n-1 (hi) and kt=n (lo):
// roll one gather vector -> 20 bperms/tile (was 32).
// ---------------------------------------------------------------------------
__launch_bounds__(256)
__global__ void attn_kernel(const short* __restrict__ Qu,
                            const short* __restrict__ Qv,
                            const short* __restrict__ Kb,
                            const short* __restrict__ Vt,
                            const short* __restrict__ Pb,
                            short* __restrict__ AO)
{
  __shared__ short Ks[64][72];      // K tile: rows=k, cols=hd (+8 pad)
  __shared__ short Vs[64][72];      // V^T tile: rows=hd, cols=k
  __shared__ short Ps[4][16][72];   // per-wave softmax probs (bf16)

  const int tid  = threadIdx.x;
  const int lane = tid & 63;
  const int wave = tid >> 6;
  const int lr   = lane & 15;
  const int lg   = lane >> 4;

  // XCD-aware swizzle: XCD c hosts blocks fid ≡ c (mod 8); give it swz ids
  // c*128..c*128+127 = bh in [c*4, c*4+4) (x-major over 32 q-tiles).
  const int fid = blockIdx.x;
  const int swz = ((fid & 7) << 7) | (fid >> 3);
  const int bh  = swz >> 5;             // b*H + h
  const int h   = bh & (Hh - 1);
  const int q0  = (swz & 31) * 64 + wave * 16;

  const short* Qu_bh = Qu + (size_t)bh * Lq * HD;
  const short* Qv_bh = Qv + (size_t)bh * Lq * HD;
  const short* Kb_bh = Kb + (size_t)bh * Lq * HD;
  const short* Vt_bh = Vt + (size_t)bh * HD * Lq;
  const short* Pl    = Pb + (size_t)h * Lq * HD + lg * 8;

  // hoisted gather constants: c = lr - dq + 15 in [0,30]
  int  addr4[4];
  bool hi4[4];
  #pragma unroll
  for (int r = 0; r < 4; ++r) {
    int c = lr - (lg * 4 + r) + 15;
    hi4[r]   = (c >= 16);
    addr4[r] = (((lane & 48) | (c & 15)) << 2);
  }

  // Q fragments (A operand): lane holds row (q0+lr), d = kk*32 + lg*8 + e
  v8bf qu[2], qv1[2], qv2[2];
  {
    int q  = q0 + lr;
    int q2 = (q + 1 < Lq) ? q + 1 : Lq - 1;   // clamped row never selected
    #pragma unroll
    for (int kk = 0; kk < 2; ++kk) {
      qu[kk]  = *(const v8bf*)(Qu_bh + (size_t)q  * HD + kk * 32 + lg * 8);
      qv1[kk] = *(const v8bf*)(Qv_bh + (size_t)q  * HD + kk * 32 + lg * 8);
      qv2[kk] = *(const v8bf*)(Qv_bh + (size_t)q2 * HD + kk * 32 + lg * 8);
    }
  }

  // K/V staging: thread -> row tid>>2, 16 cols at (tid&3)*16 (2 v8bf each)
  const int srow = tid >> 2;
  const int scol = (tid & 3) * 16;
  v8bf kpre0 = *(const v8bf*)(Kb_bh + (size_t)srow * HD + scol);
  v8bf kpre1 = *(const v8bf*)(Kb_bh + (size_t)srow * HD + scol + 8);
  v8bf vpre0 = *(const v8bf*)(Vt_bh + (size_t)srow * Lq + scol);
  v8bf vpre1 = *(const v8bf*)(Vt_bh + (size_t)srow * Lq + scol + 8);

  float m_r[4];
  v4f o_acc[5];                     // [0..3]=O columns, [4]=l (P @ ones)
  #pragma unroll
  for (int r = 0; r < 4; ++r) m_r[r] = -1e30f;
  #pragma unroll
  for (int n = 0; n < 5; ++n) o_acc[n] = v4f{0.f, 0.f, 0.f, 0.f};

  v8bf ones;
  #pragma unroll
  for (int e = 0; e < 8; ++e) ones[e] = (__bf16)1.0f;

  const float sc = 0.125f * 1.44269504088896f;   // hd^-0.5 * log2(e)

  for (int k0 = 0; k0 < Lq; k0 += 64) {
    __syncthreads();                       // prev tile's reads done
    *(v8bf*)(&Ks[srow][scol])     = kpre0;
    *(v8bf*)(&Ks[srow][scol + 8]) = kpre1;
    *(v8bf*)(&Vs[srow][scol])     = vpre0;
    *(v8bf*)(&Vs[srow][scol + 8]) = vpre1;
    __syncthreads();                       // tile visible
    if (k0 + 64 < Lq) {                    // prefetch next K/V tile
      kpre0 = *(const v8bf*)(Kb_bh + (size_t)(k0 + 64 + srow) * HD + scol);
      kpre1 = *(const v8bf*)(Kb_bh + (size_t)(k0 + 64 + srow) * HD + scol + 8);
      vpre0 = *(const v8bf*)(Vt_bh + (size_t)srow * Lq + k0 + 64 + scol);
      vpre1 = *(const v8bf*)(Vt_bh + (size_t)srow * Lq + k0 + 64 + scol + 8);
    }

    const int thr = q0 - k0 + 15;          // select T1 iff cc <= thr
    const int jb1 = 2032 + k0 - q0;        // (Lq-1) - q0 + k0 - 15
    const int jb2 = k0 - q0 - 17;

    // band P regs, 2-slot pipeline (static indices -> registers)
    v8bf p1[2][2], p2[2][2];
    auto loadB = [&](int n, int slot) {
      if (n * 16 <= thr) {
        int j = jb1 + n * 16 + lr;
        j = j < 0 ? 0 : (j > Lq - 1 ? Lq - 1 : j);
        const short* p = Pl + (size_t)j * HD;
        p1[slot][0] = *(const v8bf*)p;
        p1[slot][1] = *(const v8bf*)(p + 32);
      }
      if (n * 16 + 15 >= thr + 2) {
        int j = jb2 + n * 16 + lr;
        j = j < 0 ? 0 : (j > Lq - 1 ? Lq - 1 : j);
        const short* p = Pl + (size_t)j * HD;
        p2[slot][0] = *(const v8bf*)p;
        p2[slot][1] = *(const v8bf*)(p + 32);
      }
    };
    auto mergeB = [&](int n, int slot) -> v4f {
      v4f a1 = {0.f, 0.f, 0.f, 0.f}, a2 = {0.f, 0.f, 0.f, 0.f};
      if (n * 16 <= thr) {
        a1 = MFMA(qv1[0], p1[slot][0], a1);
        a1 = MFMA(qv1[1], p1[slot][1], a1);
      }
      if (n * 16 + 15 >= thr + 2) {
        a2 = MFMA(qv2[0], p2[slot][0], a2);
        a2 = MFMA(qv2[1], p2[slot][1], a2);
      }
      int cc = n * 16 + lr;
      v4f t;
      #pragma unroll
      for (int r = 0; r < 4; ++r)
        t[r] = (cc <= thr) ? a1[r] : ((cc == thr + 1) ? 0.f : a2[r]);
      return t;
    };

    loadB(0, 0);                           // issue under QK below
    loadB(1, 1);

    // ---- ac = Qu @ K^T (16x64) from LDS ----
    v4f s[4];
    #pragma unroll
    for (int kt = 0; kt < 4; ++kt) {
      v8bf kf0 = *(const v8bf*)(&Ks[kt * 16 + lr][lg * 8]);
      v8bf kf1 = *(const v8bf*)(&Ks[kt * 16 + lr][32 + lg * 8]);
      s[kt] = MFMA(qu[1], kf1, MFMA(qu[0], kf0, v4f{0.f, 0.f, 0.f, 0.f}));
    }

    // rolling gather: gold[r] = bperm(t[kt]), gnew[r] = bperm(t[kt+1]);
    // bd = hi4 ? gnew : gold.  5 gather vectors total (20 bperms).
    v4f gold, gnew;
    v4f tp = mergeB(0, 0);
    #pragma unroll
    for (int r = 0; r < 4; ++r) gold[r] = bperm(addr4[r], tp[r]);

    loadB(2, 0);
    v4f tc = mergeB(1, 1);
    #pragma unroll
    for (int r = 0; r < 4; ++r) gnew[r] = bperm(addr4[r], tc[r]);
    #pragma unroll
    for (int r = 0; r < 4; ++r)
      s[0][r] = (s[0][r] + (hi4[r] ? gnew[r] : gold[r])) * sc;
    gold = gnew;

    loadB(3, 1);
    tc = mergeB(2, 0);
    #pragma unroll
    for (int r = 0; r < 4; ++r) gnew[r] = bperm(addr4[r], tc[r]);
    #pragma unroll
    for (int r = 0; r < 4; ++r)
      s[1][r] = (s[1][r] + (hi4[r] ? gnew[r] : gold[r])) * sc;
    gold = gnew;

    loadB(4, 0);
    tc = mergeB(3, 1);
    #pragma unroll
    for (int r = 0; r < 4; ++r) gnew[r] = bperm(addr4[r], tc[r]);
    #pragma unroll
    for (int r = 0; r < 4; ++r)
      s[2][r] = (s[2][r] + (hi4[r] ? gnew[r] : gold[r])) * sc;
    gold = gnew;

    tc = mergeB(4, 0);
    #pragma unroll
    for (int r = 0; r < 4; ++r) gnew[r] = bperm(addr4[r], tc[r]);
    #pragma unroll
    for (int r = 0; r < 4; ++r)
      s[3][r] = (s[3][r] + (hi4[r] ? gnew[r] : gold[r])) * sc;

    // ---- online softmax (exp2 domain, DPP rowmax, exact defer-max) ----
    float rmax[4];
    float need = -1e30f;
    #pragma unroll
    for (int r = 0; r < 4; ++r) {
      float m0 = fmaxf(fmaxf(s[0][r], s[1][r]), fmaxf(s[2][r], s[3][r]));
      rmax[r] = rowmax16(m0);
      need = fmaxf(need, rmax[r] - m_r[r]);
    }
    if (!__all(need <= 0.f)) {             // rescale only when a max grew
      #pragma unroll
      for (int r = 0; r < 4; ++r) {
        float mnew  = fmaxf(m_r[r], rmax[r]);
        float alpha = exp2g(m_r[r] - mnew);
        m_r[r] = mnew;
        #pragma unroll
        for (int n = 0; n < 5; ++n)
          o_acc[n][r] *= alpha;
      }
    }
    #pragma unroll
    for (int r = 0; r < 4; ++r) {
      #pragma unroll
      for (int kt = 0; kt < 4; ++kt) {
        float p = exp2g(s[kt][r] - m_r[r]);
        Ps[wave][lg * 4 + r][kt * 16 + lr] = f2bf(p);
      }
    }
    asm volatile("s_waitcnt lgkmcnt(0)" ::: "memory");
    __builtin_amdgcn_sched_barrier(0);

    // ---- PV: O += P @ V, l += P @ 1 ----
    #pragma unroll
    for (int kk = 0; kk < 2; ++kk) {
      v8bf pa = *(const v8bf*)(&Ps[wave][lr][kk * 32 + lg * 8]);
      #pragma unroll
      for (int n = 0; n < 4; ++n) {
        v8bf vb = *(const v8bf*)(&Vs[n * 16 + lr][kk * 32 + lg * 8]);
        o_acc[n] = MFMA(pa, vb, o_acc[n]);
      }
      o_acc[4] = MFMA(pa, ones, o_acc[4]);
    }
  }

  // ---- normalize + write AO (B, L, H*HD) bf16 ----
  const int b = bh >> 4;
  #pragma unroll
  for (int r = 0; r < 4; ++r) {
    float inv = 1.0f / o_acc[4][r];
    int q = q0 + lg * 4 + r;
    #pragma unroll
    for (int n = 0; n < 4; ++n) {
      int hd = n * 16 + lr;
      AO[((size_t)b * Lq + q) * Dm + h * HD + hd] = f2bf(o_acc[n][r] * inv);
    }
  }
}

// ---------------------------------------------------------------------------
extern "C" void kernel_launch(void* const* d_in, const int* in_sizes, int n_in,
                              void* d_out, int out_size, void* d_ws, size_t ws_size,
                              hipStream_t stream)
{
  (void)in_sizes; (void)n_in; (void)out_size; (void)ws_size;
  const float* x    = (const float*)d_in[0];
  const float* pos  = (const float*)d_in[1];
  const float* Wq   = (const float*)d_in[2];
  const float* bq   = (const float*)d_in[3];
  const float* Wk   = (const float*)d_in[4];
  const float* bk   = (const float*)d_in[5];
  const float* Wv   = (const float*)d_in[6];
  const float* bv   = (const float*)d_in[7];
  const float* Wpos = (const float*)d_in[8];
  const float* pu   = (const float*)d_in[9];
  const float* pvb  = (const float*)d_in[10];
  const float* Wo   = (const float*)d_in[11];
  const float* bo   = (const float*)d_in[12];
  float* out = (float*)d_out;

  // ws layout (shorts), 56 MB total:
  //   Qu 4M | Qv 4M | Kb 4M | Vt 4M | Pb 2M | AO 4M | xb 4M | posb 2M
  // Aliases (stream-ordered, lifetime-disjoint):
  //   Wqb/Wkb/Wvb/Wpb (1M each) live in AO until attn writes AO;
  //   Wob (1M) lives in xb after gemm_qkvp is done with xb.
  short* Qu   = (short*)d_ws;
  short* Qv   = Qu   + (size_t)4 * 1024 * 1024;
  short* Kbuf = Qv   + (size_t)4 * 1024 * 1024;
  short* Vt   = Kbuf + (size_t)4 * 1024 * 1024;
  short* Pb   = Vt   + (size_t)4 * 1024 * 1024;
  short* AO   = Pb   + (size_t)2 * 1024 * 1024;
  short* xb   = AO   + (size_t)4 * 1024 * 1024;
  short* posb = xb   + (size_t)4 * 1024 * 1024;
  short* Wqb  = AO;
  short* Wkb  = AO + (size_t)1 * 1024 * 1024;
  short* Wvb  = AO + (size_t)2 * 1024 * 1024;
  short* Wpb  = AO + (size_t)3 * 1024 * 1024;
  short* Wob  = xb;

  dim3 blk(256);
  cvt_bf16<<<dim3(2048), blk, 0, stream>>>(x,    xb,   524288);
  cvt_bf16<<<dim3(1024), blk, 0, stream>>>(pos,  posb, 262144);
  cvt_bf16<<<dim3(512),  blk, 0, stream>>>(Wq,   Wqb,  131072);
  cvt_bf16<<<dim3(512),  blk, 0, stream>>>(Wk,   Wkb,  131072);
  cvt_bf16<<<dim3(512),  blk, 0, stream>>>(Wv,   Wvb,  131072);
  cvt_bf16<<<dim3(512),  blk, 0, stream>>>(Wpos, Wpb,  131072);
  gemm_qkvp<<<dim3(16, 64, 4), blk, 0, stream>>>(
      xb, posb, Wqb, Wkb, Wvb, Wpb, bq, bk, bv, pu, pvb,
      Qu, Qv, Kbuf, Vt, Pb);
  cvt_bf16<<<dim3(512),  blk, 0, stream>>>(Wo,   Wob,  131072);
  attn_kernel<<<dim3(1024), blk, 0, stream>>>(Qu, Qv, Kbuf, Vt, Pb, AO);
  gemm_out<<<dim3(16, 64), blk, 0, stream>>>(AO, Wob, bo, out);
}

// Round 8
// 333.185 us; speedup vs baseline: 1.7934x; 1.0201x over previous
//
#include <hip/hip_runtime.h>
#include <hip/hip_bf16.h>

// Problem constants
constexpr int Lq = 2048;   // sequence length
constexpr int Dm = 1024;   // model dim
constexpr int Hh = 16;     // heads
constexpr int HD = 64;     // head dim

typedef __bf16 v8bf __attribute__((ext_vector_type(8)));
typedef short  v4s  __attribute__((ext_vector_type(4)));
typedef float  v4f  __attribute__((ext_vector_type(4)));

#define DEV static __device__ __forceinline__

DEV short f2bf(float f) {
  return (short)__builtin_bit_cast(unsigned short, __float2bfloat16(f));
}

DEV v4f MFMA(v8bf a, v8bf b, v4f c) {
  return __builtin_amdgcn_mfma_f32_16x16x32_bf16(a, b, c, 0, 0, 0);
}

// DPP cross-lane (VALU pipe): 16-lane reduce = xor1,xor2,half_mirror,mirror
template<int CTRL>
DEV float dppf(float x) {
  return __builtin_bit_cast(float, __builtin_amdgcn_update_dpp(
      0, __builtin_bit_cast(int, x), CTRL, 0xF, 0xF, true));
}
DEV float rowmax16(float x) {
  x = fmaxf(x, dppf<0xB1>(x));    // quad_perm [1,0,3,2]
  x = fmaxf(x, dppf<0x4E>(x));    // quad_perm [2,3,0,1]
  x = fmaxf(x, dppf<0x141>(x));   // row_half_mirror
  x = fmaxf(x, dppf<0x140>(x));   // row_mirror
  return x;
}

DEV float bperm(int byteaddr, float x) {
  return __builtin_bit_cast(float,
      __builtin_amdgcn_ds_bpermute(byteaddr, __builtin_bit_cast(int, x)));
}

#if __has_builtin(__builtin_amdgcn_exp2f)
DEV float exp2g(float x) { return __builtin_amdgcn_exp2f(x); }
#else
DEV float exp2g(float x) { return exp2f(x); }
#endif

DEV v4s cvt4(float4 v) {
  v4s w; w[0] = f2bf(v.x); w[1] = f2bf(v.y); w[2] = f2bf(v.z); w[3] = f2bf(v.w);
  return w;
}

// ---------------------------------------------------------------------------
// Batched fp32 -> bf16 convert: 7 segments, one launch (8 elems/thread).
// ---------------------------------------------------------------------------
struct CvtSeg { const float* src; short* dst; int n8; };
struct CvtJobs { CvtSeg seg[7]; };

__launch_bounds__(256)
__global__ void cvt_multi(CvtJobs j)
{
  int rem = blockIdx.x * 256 + threadIdx.x;
  #pragma unroll
  for (int s = 0; s < 7; ++s) {
    if (rem < j.seg[s].n8) {
      const float* in = j.seg[s].src;
      short* out = j.seg[s].dst;
      float4 a = *(const float4*)(in + (size_t)rem * 8);
      float4 b = *(const float4*)(in + (size_t)rem * 8 + 4);
      *(v4s*)(out + (size_t)rem * 8)     = cvt4(a);
      *(v4s*)(out + (size_t)rem * 8 + 4) = cvt4(b);
      return;
    }
    rem -= j.seg[s].n8;
  }
}

// ---------------------------------------------------------------------------
// Fused projection GEMM: C[i,o] = sum_k A[i,k]*W[o,k] (+epilogue per z)
// A, W bf16 (pre-converted). 64x64 tile, BK=64, 4 waves, reg-prefetched tiles.
// z=0: Q -> Qu = y+bq+pu  (B,H,L,HD)   (Qv derived in attn from pvb-pu)
// z=1: K -> Kb (B,H,L,HD)
// z=2: V -> Vt (B,H,HD,L)  transposed
// z=3: P -> Pb (H,L,HD)    (M=2048: upper half of grid returns)
// ---------------------------------------------------------------------------
__launch_bounds__(256)
__global__ void gemm_qkvp(const short* __restrict__ xb,
                          const short* __restrict__ posb,
                          const short* __restrict__ Wqb, const short* __restrict__ Wkb,
                          const short* __restrict__ Wvb, const short* __restrict__ Wpb,
                          const float* __restrict__ bq, const float* __restrict__ bk,
                          const float* __restrict__ bv,
                          const float* __restrict__ pu,
                          short* __restrict__ Qu,
                          short* __restrict__ Kb, short* __restrict__ Vt,
                          short* __restrict__ Pb)
{
  const int z    = blockIdx.z;
  const int row0 = blockIdx.y * 64;
  const int col0 = blockIdx.x * 64;
  if (z == 3 && row0 >= Lq) return;
  const short* A = (z == 3) ? posb : xb;
  const short* W = (z == 0) ? Wqb : (z == 1) ? Wkb : (z == 2) ? Wvb : Wpb;

  __shared__ short As[64][72];   // +8 pad
  __shared__ short Bs[64][72];

  const int tid  = threadIdx.x;
  const int lane = tid & 63;
  const int wave = tid >> 6;
  const int lr   = lane & 15;
  const int lg   = lane >> 4;
  const int wr   = (wave >> 1) * 32;
  const int wc   = (wave & 1) * 32;
  const int srow = tid >> 2;
  const int scol = (tid & 3) * 16;

  const short* Arow = A + (size_t)(row0 + srow) * Dm + scol;
  const short* Wrow = W + (size_t)(col0 + srow) * Dm + scol;

  v8bf a0 = *(const v8bf*)(Arow);
  v8bf a1 = *(const v8bf*)(Arow + 8);
  v8bf b0 = *(const v8bf*)(Wrow);
  v8bf b1 = *(const v8bf*)(Wrow + 8);

  v4f acc[2][2] = {};

  for (int k0 = 0; k0 < Dm; k0 += 64) {
    __syncthreads();
    *(v8bf*)(&As[srow][scol])     = a0;
    *(v8bf*)(&As[srow][scol + 8]) = a1;
    *(v8bf*)(&Bs[srow][scol])     = b0;
    *(v8bf*)(&Bs[srow][scol + 8]) = b1;
    __syncthreads();
    if (k0 + 64 < Dm) {
      a0 = *(const v8bf*)(Arow + k0 + 64);
      a1 = *(const v8bf*)(Arow + k0 + 72);
      b0 = *(const v8bf*)(Wrow + k0 + 64);
      b1 = *(const v8bf*)(Wrow + k0 + 72);
    }

    #pragma unroll
    for (int kk = 0; kk < 2; ++kk) {
      v8bf af[2], bfr[2];
      #pragma unroll
      for (int sm = 0; sm < 2; ++sm)
        af[sm] = *(const v8bf*)(&As[wr + sm * 16 + lr][kk * 32 + lg * 8]);
      #pragma unroll
      for (int sn = 0; sn < 2; ++sn)
        bfr[sn] = *(const v8bf*)(&Bs[wc + sn * 16 + lr][kk * 32 + lg * 8]);
      #pragma unroll
      for (int sm = 0; sm < 2; ++sm)
        #pragma unroll
        for (int sn = 0; sn < 2; ++sn)
          acc[sm][sn] = MFMA(af[sm], bfr[sn], acc[sm][sn]);
    }
  }

  // ---- epilogue (C frag: col = lane&15, row = (lane>>4)*4 + r) ----
  #pragma unroll
  for (int sm = 0; sm < 2; ++sm) {
    #pragma unroll
    for (int sn = 0; sn < 2; ++sn) {
      #pragma unroll
      for (int r = 0; r < 4; ++r) {
        int i = row0 + wr + sm * 16 + lg * 4 + r;
        int o = col0 + wc + sn * 16 + lr;
        float val = acc[sm][sn][r];
        int b = i >> 11, l = i & 2047;
        int hh = o >> 6, hd = o & 63;
        if (z == 0) {
          size_t idx = (((size_t)(b * Hh + hh)) * Lq + l) * HD + hd;
          Qu[idx] = f2bf(val + bq[o] + pu[o]);
        } else if (z == 1) {
          val += bk[o];
          size_t idx = (((size_t)(b * Hh + hh)) * Lq + l) * HD + hd;
          Kb[idx] = f2bf(val);
        } else if (z == 2) {
          val += bv[o];
          size_t idx = (((size_t)(b * Hh + hh)) * HD + hd) * Lq + l;
          Vt[idx] = f2bf(val);
        } else {
          size_t idx = ((size_t)hh * Lq + i) * HD + hd;
          Pb[idx] = f2bf(val);
        }
      }
    }
  }
}

// ---------------------------------------------------------------------------
// Output GEMM: out = AO @ Wo^T + bo (AO, Wo bf16; out fp32)
// ---------------------------------------------------------------------------
__launch_bounds__(256)
__global__ void gemm_out(const short* __restrict__ A,
                         const short* __restrict__ W,
                         const float* __restrict__ bias,
                         float* __restrict__ out)
{
  __shared__ short As[64][72];
  __shared__ short Bs[64][72];

  const int tid  = threadIdx.x;
  const int lane = tid & 63;
  const int wave = tid >> 6;
  const int lr   = lane & 15;
  const int lg   = lane >> 4;
  const int row0 = blockIdx.y * 64;
  const int col0 = blockIdx.x * 64;
  const int wr   = (wave >> 1) * 32;
  const int wc   = (wave & 1) * 32;
  const int srow = tid >> 2;
  const int scol = (tid & 3) * 16;

  const short* Arow = A + (size_t)(row0 + srow) * Dm + scol;
  const short* Wrow = W + (size_t)(col0 + srow) * Dm + scol;

  v8bf a0 = *(const v8bf*)(Arow);
  v8bf a1 = *(const v8bf*)(Arow + 8);
  v8bf b0 = *(const v8bf*)(Wrow);
  v8bf b1 = *(const v8bf*)(Wrow + 8);

  v4f acc[2][2] = {};

  for (int k0 = 0; k0 < Dm; k0 += 64) {
    __syncthreads();
    *(v8bf*)(&As[srow][scol])     = a0;
    *(v8bf*)(&As[srow][scol + 8]) = a1;
    *(v8bf*)(&Bs[srow][scol])     = b0;
    *(v8bf*)(&Bs[srow][scol + 8]) = b1;
    __syncthreads();
    if (k0 + 64 < Dm) {
      a0 = *(const v8bf*)(Arow + k0 + 64);
      a1 = *(const v8bf*)(Arow + k0 + 72);
      b0 = *(const v8bf*)(Wrow + k0 + 64);
      b1 = *(const v8bf*)(Wrow + k0 + 72);
    }

    #pragma unroll
    for (int kk = 0; kk < 2; ++kk) {
      v8bf af[2], bfr[2];
      #pragma unroll
      for (int sm = 0; sm < 2; ++sm)
        af[sm] = *(const v8bf*)(&As[wr + sm * 16 + lr][kk * 32 + lg * 8]);
      #pragma unroll
      for (int sn = 0; sn < 2; ++sn)
        bfr[sn] = *(const v8bf*)(&Bs[wc + sn * 16 + lr][kk * 32 + lg * 8]);
      #pragma unroll
      for (int sm = 0; sm < 2; ++sm)
        #pragma unroll
        for (int sn = 0; sn < 2; ++sn)
          acc[sm][sn] = MFMA(af[sm], bfr[sn], acc[sm][sn]);
    }
  }

  #pragma unroll
  for (int sm = 0; sm < 2; ++sm)
    #pragma unroll
    for (int sn = 0; sn < 2; ++sn)
      #pragma unroll
      for (int r = 0; r < 4; ++r) {
        int i = row0 + wr + sm * 16 + lg * 4 + r;
        int o = col0 + wc + sn * 16 + lr;
        out[(size_t)i * Dm + o] = acc[sm][sn][r] + bias[o];
      }
}

// ---------------------------------------------------------------------------
// Fused rel-pos flash attention, v8 = v7 + 2-way K-SPLIT (flash-decoding).
// 2048 blocks: each handles 64 q-rows x HALF the k-range (16 tiles), writing
// a per-half normalized partial AOh = O/l (bf16) plus (m, l) fp32; a merge
// kernel combines halves. 5 blocks/CU resident -> 20 waves/CU (was 16,
// grid-limited) -- the kernel is dependency-chain latency-bound, so added
// wave overlap is the lever.
// XCD swizzle: fid&7 = XCD; each XCD owns 4 bh (all q-tiles, both halves)
// -> K/V/P working set ~3 MB fits per-XCD L2 (proven R7: FETCH 207->20MB).
// Qv derived in prologue: qv = qu + (pvb - pu) (saves Qv buffer + stores).
// rel_shift closed form:
//   k <= q   : bd[q,   L-1-q+k]
//   k == q+1 : 0
//   k >  q+1 : bd[q+1, k-q-2]     (row-wrap artifact of the reshape trick)
// ---------------------------------------------------------------------------
__launch_bounds__(256)
__global__ void attn_kernel(const short* __restrict__ Qu,
                            const short* __restrict__ Kb,
                            const short* __restrict__ Vt,
                            const short* __restrict__ Pb,
                            const float* __restrict__ pu,
                            const float* __restrict__ pvb,
                            short* __restrict__ Op0,
                            short* __restrict__ Op1,
                            float* __restrict__ ml)
{
  __shared__ short Ks[64][72];      // K tile: rows=k, cols=hd (+8 pad)
  __shared__ short Vs[64][72];      // V^T tile: rows=hd, cols=k
  __shared__ short Ps[4][16][72];   // per-wave softmax probs (bf16)

  const int tid  = threadIdx.x;
  const int lane = tid & 63;
  const int wave = tid >> 6;
  const int lr   = lane & 15;
  const int lg   = lane >> 4;

  // decode swizzled block id: xcd | bh-local | qt | half
  const int fid  = blockIdx.x;
  const int idx  = fid >> 3;                  // 0..255
  const int bh   = (fid & 7) * 4 + (idx >> 6);
  const int h    = bh & (Hh - 1);
  const int qt   = (idx & 63) >> 1;
  const int half = idx & 1;
  const int q0   = qt * 64 + wave * 16;
  const int kbeg = half * (Lq / 2);
  const int kend = kbeg + Lq / 2;

  const short* Qu_bh = Qu + (size_t)bh * Lq * HD;
  const short* Kb_bh = Kb + (size_t)bh * Lq * HD;
  const short* Vt_bh = Vt + (size_t)bh * HD * Lq;
  const short* Pl    = Pb + (size_t)h * Lq * HD + lg * 8;

  // hoisted gather constants: c = lr - dq + 15 in [0,30]
  int  addr4[4];
  bool hi4[4];
  #pragma unroll
  for (int r = 0; r < 4; ++r) {
    int c = lr - (lg * 4 + r) + 15;
    hi4[r]   = (c >= 16);
    addr4[r] = (((lane & 48) | (c & 15)) << 2);
  }

  // Q fragments: lane holds row (q0+lr), d = kk*32 + lg*8 + e.
  // qv1 = qu + (pvb-pu); qv2 = qu(q+1) + (pvb-pu)  (delta in fp32, 1 rounding)
  v8bf qu[2], qv1[2], qv2[2];
  {
    int q  = q0 + lr;
    int q2 = (q + 1 < Lq) ? q + 1 : Lq - 1;   // clamped row never selected
    #pragma unroll
    for (int kk = 0; kk < 2; ++kk) {
      qu[kk] = *(const v8bf*)(Qu_bh + (size_t)q  * HD + kk * 32 + lg * 8);
      v8bf qu2 = *(const v8bf*)(Qu_bh + (size_t)q2 * HD + kk * 32 + lg * 8);
      const float* pup = pu  + h * HD + kk * 32 + lg * 8;
      const float* pvp = pvb + h * HD + kk * 32 + lg * 8;
      #pragma unroll
      for (int e = 0; e < 8; ++e) {
        float dd = pvp[e] - pup[e];
        qv1[kk][e] = (__bf16)((float)qu[kk][e] + dd);
        qv2[kk][e] = (__bf16)((float)qu2[e]    + dd);
      }
    }
  }

  // K/V staging: thread -> row tid>>2, 16 cols at (tid&3)*16 (2 v8bf each)
  const int srow = tid >> 2;
  const int scol = (tid & 3) * 16;
  v8bf kpre0 = *(const v8bf*)(Kb_bh + (size_t)(kbeg + srow) * HD + scol);
  v8bf kpre1 = *(const v8bf*)(Kb_bh + (size_t)(kbeg + srow) * HD + scol + 8);
  v8bf vpre0 = *(const v8bf*)(Vt_bh + (size_t)srow * Lq + kbeg + scol);
  v8bf vpre1 = *(const v8bf*)(Vt_bh + (size_t)srow * Lq + kbeg + scol + 8);

  float m_r[4];
  v4f o_acc[5];                     // [0..3]=O columns, [4]=l (P @ ones)
  #pragma unroll
  for (int r = 0; r < 4; ++r) m_r[r] = -1e30f;
  #pragma unroll
  for (int n = 0; n < 5; ++n) o_acc[n] = v4f{0.f, 0.f, 0.f, 0.f};

  v8bf ones;
  #pragma unroll
  for (int e = 0; e < 8; ++e) ones[e] = (__bf16)1.0f;

  const float sc = 0.125f * 1.44269504088896f;   // hd^-0.5 * log2(e)

  for (int k0 = kbeg; k0 < kend; k0 += 64) {
    __syncthreads();                       // prev tile's reads done
    *(v8bf*)(&Ks[srow][scol])     = kpre0;
    *(v8bf*)(&Ks[srow][scol + 8]) = kpre1;
    *(v8bf*)(&Vs[srow][scol])     = vpre0;
    *(v8bf*)(&Vs[srow][scol + 8]) = vpre1;
    __syncthreads();                       // tile visible
    if (k0 + 64 < kend) {                  // prefetch next K/V tile
      kpre0 = *(const v8bf*)(Kb_bh + (size_t)(k0 + 64 + srow) * HD + scol);
      kpre1 = *(const v8bf*)(Kb_bh + (size_t)(k0 + 64 + srow) * HD + scol + 8);
      vpre0 = *(const v8bf*)(Vt_bh + (size_t)srow * Lq + k0 + 64 + scol);
      vpre1 = *(const v8bf*)(Vt_bh + (size_t)srow * Lq + k0 + 64 + scol + 8);
    }

    const int thr = q0 - k0 + 15;          // select T1 iff cc <= thr
    const int jb1 = 2032 + k0 - q0;        // (Lq-1) - q0 + k0 - 15
    const int jb2 = k0 - q0 - 17;

    // band P regs, 2-slot pipeline (static indices -> registers)
    v8bf p1[2][2], p2[2][2];
    auto loadB = [&](int n, int slot) {
      if (n * 16 <= thr) {
        int j = jb1 + n * 16 + lr;
        j = j < 0 ? 0 : (j > Lq - 1 ? Lq - 1 : j);
        const short* p = Pl + (size_t)j * HD;
        p1[slot][0] = *(const v8bf*)p;
        p1[slot][1] = *(const v8bf*)(p + 32);
      }
      if (n * 16 + 15 >= thr + 2) {
        int j = jb2 + n * 16 + lr;
        j = j < 0 ? 0 : (j > Lq - 1 ? Lq - 1 : j);
        const short* p = Pl + (size_t)j * HD;
        p2[slot][0] = *(const v8bf*)p;
        p2[slot][1] = *(const v8bf*)(p + 32);
      }
    };
    auto mergeB = [&](int n, int slot) -> v4f {
      v4f a1 = {0.f, 0.f, 0.f, 0.f}, a2 = {0.f, 0.f, 0.f, 0.f};
      if (n * 16 <= thr) {
        a1 = MFMA(qv1[0], p1[slot][0], a1);
        a1 = MFMA(qv1[1], p1[slot][1], a1);
      }
      if (n * 16 + 15 >= thr + 2) {
        a2 = MFMA(qv2[0], p2[slot][0], a2);
        a2 = MFMA(qv2[1], p2[slot][1], a2);
      }
      int cc = n * 16 + lr;
      v4f t;
      #pragma unroll
      for (int r = 0; r < 4; ++r)
        t[r] = (cc <= thr) ? a1[r] : ((cc == thr + 1) ? 0.f : a2[r]);
      return t;
    };

    loadB(0, 0);                           // issue under QK below
    loadB(1, 1);

    // ---- ac = Qu @ K^T (16x64) from LDS ----
    v4f s[4];
    __builtin_amdgcn_s_setprio(1);
    #pragma unroll
    for (int kt = 0; kt < 4; ++kt) {
      v8bf kf0 = *(const v8bf*)(&Ks[kt * 16 + lr][lg * 8]);
      v8bf kf1 = *(const v8bf*)(&Ks[kt * 16 + lr][32 + lg * 8]);
      s[kt] = MFMA(qu[1], kf1, MFMA(qu[0], kf0, v4f{0.f, 0.f, 0.f, 0.f}));
    }
    __builtin_amdgcn_s_setprio(0);

    // rolling gather: gold[r] = bperm(t[kt]), gnew[r] = bperm(t[kt+1]);
    // bd = hi4 ? gnew : gold.  5 gather vectors total (20 bperms).
    v4f gold, gnew;
    v4f tp = mergeB(0, 0);
    #pragma unroll
    for (int r = 0; r < 4; ++r) gold[r] = bperm(addr4[r], tp[r]);

    loadB(2, 0);
    v4f tc = mergeB(1, 1);
    #pragma unroll
    for (int r = 0; r < 4; ++r) gnew[r] = bperm(addr4[r], tc[r]);
    #pragma unroll
    for (int r = 0; r < 4; ++r)
      s[0][r] = (s[0][r] + (hi4[r] ? gnew[r] : gold[r])) * sc;
    gold = gnew;

    loadB(3, 1);
    tc = mergeB(2, 0);
    #pragma unroll
    for (int r = 0; r < 4; ++r) gnew[r] = bperm(addr4[r], tc[r]);
    #pragma unroll
    for (int r = 0; r < 4; ++r)
      s[1][r] = (s[1][r] + (hi4[r] ? gnew[r] : gold[r])) * sc;
    gold = gnew;

    loadB(4, 0);
    tc = mergeB(3, 1);
    #pragma unroll
    for (int r = 0; r < 4; ++r) gnew[r] = bperm(addr4[r], tc[r]);
    #pragma unroll
    for (int r = 0; r < 4; ++r)
      s[2][r] = (s[2][r] + (hi4[r] ? gnew[r] : gold[r])) * sc;
    gold = gnew;

    tc = mergeB(4, 0);
    #pragma unroll
    for (int r = 0; r < 4; ++r) gnew[r] = bperm(addr4[r], tc[r]);
    #pragma unroll
    for (int r = 0; r < 4; ++r)
      s[3][r] = (s[3][r] + (hi4[r] ? gnew[r] : gold[r])) * sc;

    // ---- online softmax (exp2 domain, DPP rowmax, exact defer-max) ----
    float rmax[4];
    float need = -1e30f;
    #pragma unroll
    for (int r = 0; r < 4; ++r) {
      float m0 = fmaxf(fmaxf(s[0][r], s[1][r]), fmaxf(s[2][r], s[3][r]));
      rmax[r] = rowmax16(m0);
      need = fmaxf(need, rmax[r] - m_r[r]);
    }
    if (!__all(need <= 0.f)) {             // rescale only when a max grew
      #pragma unroll
      for (int r = 0; r < 4; ++r) {
        float mnew  = fmaxf(m_r[r], rmax[r]);
        float alpha = exp2g(m_r[r] - mnew);
        m_r[r] = mnew;
        #pragma unroll
        for (int n = 0; n < 5; ++n)
          o_acc[n][r] *= alpha;
      }
    }
    #pragma unroll
    for (int r = 0; r < 4; ++r) {
      #pragma unroll
      for (int kt = 0; kt < 4; ++kt) {
        float p = exp2g(s[kt][r] - m_r[r]);
        Ps[wave][lg * 4 + r][kt * 16 + lr] = f2bf(p);
      }
    }
    asm volatile("s_waitcnt lgkmcnt(0)" ::: "memory");
    __builtin_amdgcn_sched_barrier(0);

    // ---- PV: O += P @ V, l += P @ 1 ----
    __builtin_amdgcn_s_setprio(1);
    #pragma unroll
    for (int kk = 0; kk < 2; ++kk) {
      v8bf pa = *(const v8bf*)(&Ps[wave][lr][kk * 32 + lg * 8]);
      #pragma unroll
      for (int n = 0; n < 4; ++n) {
        v8bf vb = *(const v8bf*)(&Vs[n * 16 + lr][kk * 32 + lg * 8]);
        o_acc[n] = MFMA(pa, vb, o_acc[n]);
      }
      o_acc[4] = MFMA(pa, ones, o_acc[4]);
    }
    __builtin_amdgcn_s_setprio(0);
  }

  // ---- write partial: AOh = O/l (bf16, (bh,q,hd)), plus m,l (fp32) ----
  short* Oph = half ? Op1 : Op0;
  float* mlh = ml + (size_t)half * 32 * Lq * 2;
  #pragma unroll
  for (int r = 0; r < 4; ++r) {
    float inv = 1.0f / o_acc[4][r];
    int q = q0 + lg * 4 + r;
    #pragma unroll
    for (int n = 0; n < 4; ++n) {
      int hd = n * 16 + lr;
      Oph[((size_t)bh * Lq + q) * HD + hd] = f2bf(o_acc[n][r] * inv);
    }
    if (lr == 0) {
      mlh[((size_t)bh * Lq + q) * 2 + 0] = m_r[r];
      mlh[((size_t)bh * Lq + q) * 2 + 1] = o_acc[4][r];
    }
  }
}

// ---------------------------------------------------------------------------
// Merge the two K-halves: AO = (AOh0*w0 + AOh1*w1), w_h = l_h*2^(m_h-m) / sum.
// One thread per 8 hd elements; writes AO in (B, L, H*HD) bf16.
// ---------------------------------------------------------------------------
__launch_bounds__(256)
__global__ void merge_halves(const short* __restrict__ Op0,
                             const short* __restrict__ Op1,
                             const float* __restrict__ ml,
                             short* __restrict__ AO)
{
  int t   = blockIdx.x * 256 + threadIdx.x;   // 524288 tasks
  int row = t >> 3;                           // bh*Lq + q
  int hd8 = (t & 7) * 8;

  float m0 = ml[(size_t)row * 2];
  float l0 = ml[(size_t)row * 2 + 1];
  float m1 = ml[((size_t)(32 * Lq) + row) * 2];
  float l1 = ml[((size_t)(32 * Lq) + row) * 2 + 1];
  float mm = fmaxf(m0, m1);
  float a0 = exp2g(m0 - mm) * l0;
  float a1 = exp2g(m1 - mm) * l1;
  float iw = 1.0f / (a0 + a1);
  float w0 = a0 * iw, w1 = a1 * iw;

  v8bf x0 = *(const v8bf*)(Op0 + (size_t)row * HD + hd8);
  v8bf x1 = *(const v8bf*)(Op1 + (size_t)row * HD + hd8);
  v8bf res;
  #pragma unroll
  for (int e = 0; e < 8; ++e)
    res[e] = (__bf16)(w0 * (float)x0[e] + w1 * (float)x1[e]);

  int bh = row >> 11, q = row & 2047;
  int b = bh >> 4, h = bh & 15;
  *(v8bf*)(AO + ((size_t)(b * Lq + q)) * Dm + h * HD + hd8) = res;
}

// ---------------------------------------------------------------------------
extern "C" void kernel_launch(void* const* d_in, const int* in_sizes, int n_in,
                              void* d_out, int out_size, void* d_ws, size_t ws_size,
                              hipStream_t stream)
{
  (void)in_sizes; (void)n_in; (void)out_size; (void)ws_size;
  const float* x    = (const float*)d_in[0];
  const float* pos  = (const float*)d_in[1];
  const float* Wq   = (const float*)d_in[2];
  const float* bq   = (const float*)d_in[3];
  const float* Wk   = (const float*)d_in[4];
  const float* bk   = (const float*)d_in[5];
  const float* Wv   = (const float*)d_in[6];
  const float* bv   = (const float*)d_in[7];
  const float* Wpos = (const float*)d_in[8];
  const float* pu   = (const float*)d_in[9];
  const float* pvb  = (const float*)d_in[10];
  const float* Wo   = (const float*)d_in[11];
  const float* bo   = (const float*)d_in[12];
  float* out = (float*)d_out;

  // ws layout (shorts), 29M shorts = 58 MB, with lifetime-disjoint aliases:
  //   Qu 4M | Kb 4M | Vt 4M | Pb 2M | xb 4M (->AO) | posb 2M (->ml)
  //   | Wb 4M = Wqb..Wpb (->Op0) | Op1 4M | Wob 1M
  short* Qu   = (short*)d_ws;
  short* Kbuf = Qu   + (size_t)4 * 1024 * 1024;
  short* Vt   = Kbuf + (size_t)4 * 1024 * 1024;
  short* Pb   = Vt   + (size_t)4 * 1024 * 1024;
  short* xb   = Pb   + (size_t)2 * 1024 * 1024;
  short* posb = xb   + (size_t)4 * 1024 * 1024;
  short* Wqb  = posb + (size_t)2 * 1024 * 1024;
  short* Wkb  = Wqb  + (size_t)1 * 1024 * 1024;
  short* Wvb  = Wqb  + (size_t)2 * 1024 * 1024;
  short* Wpb  = Wqb  + (size_t)3 * 1024 * 1024;
  short* Op1  = Wqb  + (size_t)4 * 1024 * 1024;
  short* Wob  = Op1  + (size_t)4 * 1024 * 1024;
  short* AO   = xb;              // alias: xb dead after gemm_qkvp
  float* ml   = (float*)posb;    // alias: posb dead after gemm_qkvp
  short* Op0  = Wqb;             // alias: weights dead after gemm_qkvp

  dim3 blk(256);
  CvtJobs jobs;
  jobs.seg[0] = {x,    xb,   524288};
  jobs.seg[1] = {pos,  posb, 262144};
  jobs.seg[2] = {Wq,   Wqb,  131072};
  jobs.seg[3] = {Wk,   Wkb,  131072};
  jobs.seg[4] = {Wv,   Wvb,  131072};
  jobs.seg[5] = {Wpos, Wpb,  131072};
  jobs.seg[6] = {Wo,   Wob,  131072};
  cvt_multi<<<dim3(5632), blk, 0, stream>>>(jobs);
  gemm_qkvp<<<dim3(16, 64, 4), blk, 0, stream>>>(
      xb, posb, Wqb, Wkb, Wvb, Wpb, bq, bk, bv, pu,
      Qu, Kbuf, Vt, Pb);
  attn_kernel<<<dim3(2048), blk, 0, stream>>>(Qu, Kbuf, Vt, Pb, pu, pvb,
                                              Op0, Op1, ml);
  merge_halves<<<dim3(2048), blk, 0, stream>>>(Op0, Op1, ml, AO);
  gemm_out<<<dim3(16, 64), blk, 0, stream>>>(AO, Wob, bo, out);
}